// Round 6
// baseline (200.980 us; speedup 1.0000x reference)
//
#include <hip/hip_runtime.h>

#define BATCH   1024
#define ASZ     256
#define EDIM    200
#define RDIM    200
#define HDIM    400
#define ACTDIM  400   // E+R
#define INDIM   800   // E+H+R
#define NRELS   500

#define BM 64
#define BN 64
#define BK 32

// ---------------------------------------------------------------------------
// K0: X_in[b] = [entity_emb[e[b]] ; H[b] ; relation_emb[q[b]]]  (float4)
// ---------------------------------------------------------------------------
__global__ __launch_bounds__(256) void k_gather_concat(
    const int* __restrict__ e, const int* __restrict__ q,
    const float* __restrict__ H,
    const float* __restrict__ ent_emb, const float* __restrict__ rel_emb,
    float* __restrict__ Xin)
{
    int b = blockIdx.x;
    int t = threadIdx.x;
    const float4* E4 = (const float4*)(ent_emb + (long)e[b] * EDIM);  // 50
    const float4* Q4 = (const float4*)(rel_emb + (long)q[b] * RDIM);  // 50
    const float4* H4 = (const float4*)(H + (long)b * HDIM);           // 100
    float4* X4 = (float4*)(Xin + (long)b * INDIM);                    // 200
    for (int i = t; i < 200; i += 256) {
        float4 v = (i < 50) ? E4[i] : (i < 150) ? H4[i - 50] : Q4[i - 150];
        X4[i] = v;
    }
}

// ---------------------------------------------------------------------------
// Split-K tiled fp32 GEMM (round-5 verified). Used for GEMM1 only.
// ---------------------------------------------------------------------------
template<int RELU, int BT>
__global__ __launch_bounds__(256) void k_gemm(
    const float* __restrict__ A, const float* __restrict__ Bm,
    const float* __restrict__ bias,
    float* __restrict__ C, float* __restrict__ Cp,
    int M, int N, int K, int kslice)
{
    __shared__ __align__(16) float As[2][BK][BM];
    __shared__ __align__(16) float Bs[2][BK][BN];

    const int t   = threadIdx.x;
    const int bn  = blockIdx.x * BN;
    const int bm  = blockIdx.y * BM;
    const int ks  = blockIdx.z;
    const int nks = gridDim.z;
    const int kbeg = ks * kslice;
    const int kend = min(K, kbeg + kslice);
    const int nk   = (kend - kbeg + BK - 1) / BK;

    const int ar  = t >> 3;            // 0..31
    const int ak4 = (t & 7) * 4;       // 0..28
    const int bkr = t >> 4;            // 0..15
    const int bnc = (t & 15) * 4;      // 0..60

    float4 a0, a1, b0, b1;

    auto fetch = [&](int kt) {
        const int k0 = kbeg + kt * BK;
        {
            int gm0 = bm + ar, gm1 = bm + ar + 32;
            int gk = k0 + ak4;
            bool kok = (gk + 4 <= kend);
            a0 = (kok && gm0 < M) ? *(const float4*)(A + (long)gm0 * K + gk)
                                  : make_float4(0.f, 0.f, 0.f, 0.f);
            a1 = (kok && gm1 < M) ? *(const float4*)(A + (long)gm1 * K + gk)
                                  : make_float4(0.f, 0.f, 0.f, 0.f);
        }
        if (BT == 0) {
            int gk0 = k0 + bkr, gk1 = k0 + bkr + 16;
            int gn = bn + bnc;
            bool nok = (gn + 4 <= N);
            b0 = (nok && gk0 < kend) ? *(const float4*)(Bm + (long)gk0 * N + gn)
                                     : make_float4(0.f, 0.f, 0.f, 0.f);
            b1 = (nok && gk1 < kend) ? *(const float4*)(Bm + (long)gk1 * N + gn)
                                     : make_float4(0.f, 0.f, 0.f, 0.f);
        } else {
            int gn0 = bn + ar, gn1 = bn + ar + 32;
            int gk = k0 + ak4;
            bool kok = (gk + 4 <= kend);
            b0 = (kok && gn0 < N) ? *(const float4*)(Bm + (long)gn0 * K + gk)
                                  : make_float4(0.f, 0.f, 0.f, 0.f);
            b1 = (kok && gn1 < N) ? *(const float4*)(Bm + (long)gn1 * K + gk)
                                  : make_float4(0.f, 0.f, 0.f, 0.f);
        }
    };

    auto stage = [&](int buf) {
        As[buf][ak4 + 0][ar] = a0.x;  As[buf][ak4 + 1][ar] = a0.y;
        As[buf][ak4 + 2][ar] = a0.z;  As[buf][ak4 + 3][ar] = a0.w;
        As[buf][ak4 + 0][ar + 32] = a1.x;  As[buf][ak4 + 1][ar + 32] = a1.y;
        As[buf][ak4 + 2][ar + 32] = a1.z;  As[buf][ak4 + 3][ar + 32] = a1.w;
        if (BT == 0) {
            *(float4*)&Bs[buf][bkr][bnc]      = b0;
            *(float4*)&Bs[buf][bkr + 16][bnc] = b1;
        } else {
            Bs[buf][ak4 + 0][ar] = b0.x;  Bs[buf][ak4 + 1][ar] = b0.y;
            Bs[buf][ak4 + 2][ar] = b0.z;  Bs[buf][ak4 + 3][ar] = b0.w;
            Bs[buf][ak4 + 0][ar + 32] = b1.x;  Bs[buf][ak4 + 1][ar + 32] = b1.y;
            Bs[buf][ak4 + 2][ar + 32] = b1.z;  Bs[buf][ak4 + 3][ar + 32] = b1.w;
        }
    };

    float acc[4][4];
#pragma unroll
    for (int i = 0; i < 4; ++i)
#pragma unroll
        for (int j = 0; j < 4; ++j) acc[i][j] = 0.f;

    const int tm = t >> 4;
    const int tn = t & 15;

    fetch(0);
    stage(0);
    __syncthreads();

    for (int kt = 0; kt < nk; ++kt) {
        const int cur = kt & 1;
        if (kt + 1 < nk) fetch(kt + 1);

#pragma unroll
        for (int kk = 0; kk < BK; ++kk) {
            const float4 a4 = *(const float4*)&As[cur][kk][tm * 4];
            const float4 b4 = *(const float4*)&Bs[cur][kk][tn * 4];
            acc[0][0] = fmaf(a4.x, b4.x, acc[0][0]);
            acc[0][1] = fmaf(a4.x, b4.y, acc[0][1]);
            acc[0][2] = fmaf(a4.x, b4.z, acc[0][2]);
            acc[0][3] = fmaf(a4.x, b4.w, acc[0][3]);
            acc[1][0] = fmaf(a4.y, b4.x, acc[1][0]);
            acc[1][1] = fmaf(a4.y, b4.y, acc[1][1]);
            acc[1][2] = fmaf(a4.y, b4.z, acc[1][2]);
            acc[1][3] = fmaf(a4.y, b4.w, acc[1][3]);
            acc[2][0] = fmaf(a4.z, b4.x, acc[2][0]);
            acc[2][1] = fmaf(a4.z, b4.y, acc[2][1]);
            acc[2][2] = fmaf(a4.z, b4.z, acc[2][2]);
            acc[2][3] = fmaf(a4.z, b4.w, acc[2][3]);
            acc[3][0] = fmaf(a4.w, b4.x, acc[3][0]);
            acc[3][1] = fmaf(a4.w, b4.y, acc[3][1]);
            acc[3][2] = fmaf(a4.w, b4.z, acc[3][2]);
            acc[3][3] = fmaf(a4.w, b4.w, acc[3][3]);
        }

        if (kt + 1 < nk) {
            __syncthreads();
            stage(cur ^ 1);
            __syncthreads();
        }
    }

    const int gn0 = bn + tn * 4;
    if (nks == 1) {
#pragma unroll
        for (int i = 0; i < 4; ++i) {
            int gm = bm + tm * 4 + i;
            if (gm >= M || gn0 >= N) continue;
            float4 v = make_float4(acc[i][0], acc[i][1], acc[i][2], acc[i][3]);
            if (bias) {
                float4 bb = *(const float4*)(bias + gn0);
                v.x += bb.x; v.y += bb.y; v.z += bb.z; v.w += bb.w;
            }
            if (RELU) {
                v.x = fmaxf(v.x, 0.f); v.y = fmaxf(v.y, 0.f);
                v.z = fmaxf(v.z, 0.f); v.w = fmaxf(v.w, 0.f);
            }
            *(float4*)(C + (long)gm * N + gn0) = v;
        }
    } else {
        float* dst = Cp + (long)ks * M * N;
#pragma unroll
        for (int i = 0; i < 4; ++i) {
            int gm = bm + tm * 4 + i;
            if (gm >= M || gn0 >= N) continue;
            float4 v = make_float4(acc[i][0], acc[i][1], acc[i][2], acc[i][3]);
            *(float4*)(dst + (long)gm * N + gn0) = v;
        }
    }
}

// ---------------------------------------------------------------------------
// Split-K reduce (round-5 verified)
// ---------------------------------------------------------------------------
template<int RELU, int HASBIAS>
__global__ __launch_bounds__(128) void k_reduce(
    const float* __restrict__ Cp, const float* __restrict__ bias,
    float* __restrict__ C, int M, int N, int nks)
{
    int m = blockIdx.x;
    int nf4 = N >> 2;
    for (int f = threadIdx.x; f < nf4; f += 128) {
        long off = (long)m * N + f * 4;
        float4 s = *(const float4*)(Cp + off);
        for (int ks = 1; ks < nks; ++ks) {
            float4 v = *(const float4*)(Cp + (long)ks * M * N + off);
            s.x += v.x; s.y += v.y; s.z += v.z; s.w += v.w;
        }
        if (HASBIAS) {
            float4 bb = *(const float4*)(bias + f * 4);
            s.x += bb.x; s.y += bb.y; s.z += bb.z; s.w += bb.w;
        }
        if (RELU) {
            s.x = fmaxf(s.x, 0.f); s.y = fmaxf(s.y, 0.f);
            s.z = fmaxf(s.z, 0.f); s.w = fmaxf(s.w, 0.f);
        }
        *(float4*)(C + off) = s;
    }
}

// ---------------------------------------------------------------------------
// Small compile-time GEMMs for weight composition.
// MODE 0: Astack[0:400]   = W2 @ Watt        (M=400,N=200,K=400, B row-major)
//         Astack[400:800] = W2[:, 0:200]     (copy, done in epilogue)
// MODE 1: Wcat[m][0:500]   = Astack[0:400] @ rel^T   (rows m<400)
//         Wcat[m][500:1000]= Astack[400:800] @ rel^T (rows m>=400)
//         (M=800,N=500,K=200, B=rel [500,200] transposed)
// MODE 2: Big = X1 @ [W2 | Wcat] + bbig      (M=1024,N=1400,K=400)
// ---------------------------------------------------------------------------
template<int MODE>
__global__ __launch_bounds__(256) void k_gemm_s(
    const float* __restrict__ A,     // M0:W2  M1:Astack  M2:X1
    const float* __restrict__ B1,    // M0:Watt M1:rel    M2:W2
    const float* __restrict__ B2,    // M2:Wcat
    const float* __restrict__ bias,  // M2:bbig
    float* __restrict__ C,           // M0:Astack M1:Wcat M2:Big
    const float* __restrict__ W2c)   // M0: W2 (copy src)
{
    constexpr int M = (MODE == 0) ? 400 : (MODE == 1) ? 800 : 1024;
    constexpr int N = (MODE == 0) ? 200 : (MODE == 1) ? 500 : 1400;
    constexpr int K = (MODE == 0) ? 400 : (MODE == 1) ? 200 : 400;
    constexpr int NK = (K + BK - 1) / BK;

    __shared__ __align__(16) float As[2][BK][BM];
    __shared__ __align__(16) float Bs[2][BK][BN];

    const int t  = threadIdx.x;
    const int bn = blockIdx.x * BN;
    const int bm = blockIdx.y * BM;

    const int ar  = t >> 3;            // 0..31
    const int ak4 = (t & 7) * 4;       // 0..28
    const int bkr = t >> 4;            // 0..15
    const int bnc = (t & 15) * 4;      // 0..60

    float4 a0, a1, b0, b1;
    const float4 z4 = make_float4(0.f, 0.f, 0.f, 0.f);

    auto fetch = [&](int kt) {
        const int k0 = kt * BK;
        {
            int gm0 = bm + ar, gm1 = bm + ar + 32;
            int gk = k0 + ak4;
            bool kok = (gk + 4 <= K);
            a0 = (kok && gm0 < M) ? *(const float4*)(A + (long)gm0 * K + gk) : z4;
            a1 = (kok && gm1 < M) ? *(const float4*)(A + (long)gm1 * K + gk) : z4;
        }
        if constexpr (MODE == 0) {
            int gk0 = k0 + bkr, gk1 = k0 + bkr + 16;
            int gn = bn + bnc;
            bool nok = (gn + 4 <= N);
            b0 = (nok && gk0 < K) ? *(const float4*)(B1 + (long)gk0 * N + gn) : z4;
            b1 = (nok && gk1 < K) ? *(const float4*)(B1 + (long)gk1 * N + gn) : z4;
        } else if constexpr (MODE == 1) {
            int gn0 = bn + ar, gn1 = bn + ar + 32;
            int gk = k0 + ak4;
            bool kok = (gk + 4 <= K);
            b0 = (kok && gn0 < N) ? *(const float4*)(B1 + (long)gn0 * K + gk) : z4;
            b1 = (kok && gn1 < N) ? *(const float4*)(B1 + (long)gn1 * K + gk) : z4;
        } else {
            int gk0 = k0 + bkr, gk1 = k0 + bkr + 16;
            int gn = bn + bnc;
            auto src = [&](int gk) -> float4 {
                if (gk >= K) return z4;
                if (gn < 400)  return *(const float4*)(B1 + (long)gk * 400 + gn);
                if (gn < 1400) return *(const float4*)(B2 + (long)gk * 1000 + (gn - 400));
                return z4;
            };
            b0 = src(gk0);
            b1 = src(gk1);
        }
    };

    auto stage = [&](int buf) {
        As[buf][ak4 + 0][ar] = a0.x;  As[buf][ak4 + 1][ar] = a0.y;
        As[buf][ak4 + 2][ar] = a0.z;  As[buf][ak4 + 3][ar] = a0.w;
        As[buf][ak4 + 0][ar + 32] = a1.x;  As[buf][ak4 + 1][ar + 32] = a1.y;
        As[buf][ak4 + 2][ar + 32] = a1.z;  As[buf][ak4 + 3][ar + 32] = a1.w;
        if constexpr (MODE == 1) {
            Bs[buf][ak4 + 0][ar] = b0.x;  Bs[buf][ak4 + 1][ar] = b0.y;
            Bs[buf][ak4 + 2][ar] = b0.z;  Bs[buf][ak4 + 3][ar] = b0.w;
            Bs[buf][ak4 + 0][ar + 32] = b1.x;  Bs[buf][ak4 + 1][ar + 32] = b1.y;
            Bs[buf][ak4 + 2][ar + 32] = b1.z;  Bs[buf][ak4 + 3][ar + 32] = b1.w;
        } else {
            *(float4*)&Bs[buf][bkr][bnc]      = b0;
            *(float4*)&Bs[buf][bkr + 16][bnc] = b1;
        }
    };

    float acc[4][4];
#pragma unroll
    for (int i = 0; i < 4; ++i)
#pragma unroll
        for (int j = 0; j < 4; ++j) acc[i][j] = 0.f;

    const int tm = t >> 4;
    const int tn = t & 15;

    fetch(0);
    stage(0);
    __syncthreads();

    for (int kt = 0; kt < NK; ++kt) {
        const int cur = kt & 1;
        if (kt + 1 < NK) fetch(kt + 1);

#pragma unroll
        for (int kk = 0; kk < BK; ++kk) {
            const float4 a4 = *(const float4*)&As[cur][kk][tm * 4];
            const float4 b4 = *(const float4*)&Bs[cur][kk][tn * 4];
            acc[0][0] = fmaf(a4.x, b4.x, acc[0][0]);
            acc[0][1] = fmaf(a4.x, b4.y, acc[0][1]);
            acc[0][2] = fmaf(a4.x, b4.z, acc[0][2]);
            acc[0][3] = fmaf(a4.x, b4.w, acc[0][3]);
            acc[1][0] = fmaf(a4.y, b4.x, acc[1][0]);
            acc[1][1] = fmaf(a4.y, b4.y, acc[1][1]);
            acc[1][2] = fmaf(a4.y, b4.z, acc[1][2]);
            acc[1][3] = fmaf(a4.y, b4.w, acc[1][3]);
            acc[2][0] = fmaf(a4.z, b4.x, acc[2][0]);
            acc[2][1] = fmaf(a4.z, b4.y, acc[2][1]);
            acc[2][2] = fmaf(a4.z, b4.z, acc[2][2]);
            acc[2][3] = fmaf(a4.z, b4.w, acc[2][3]);
            acc[3][0] = fmaf(a4.w, b4.x, acc[3][0]);
            acc[3][1] = fmaf(a4.w, b4.y, acc[3][1]);
            acc[3][2] = fmaf(a4.w, b4.z, acc[3][2]);
            acc[3][3] = fmaf(a4.w, b4.w, acc[3][3]);
        }

        if (kt + 1 < NK) {
            __syncthreads();
            stage(cur ^ 1);
            __syncthreads();
        }
    }

    const int gn0 = bn + tn * 4;
#pragma unroll
    for (int i = 0; i < 4; ++i) {
        int gm = bm + tm * 4 + i;
        if (gm >= M || gn0 >= N) continue;
        float4 v = make_float4(acc[i][0], acc[i][1], acc[i][2], acc[i][3]);
        if constexpr (MODE == 0) {
            *(float4*)(C + (long)gm * 200 + gn0) = v;                 // W2@Watt
            *(float4*)(C + (long)(400 + gm) * 200 + gn0) =
                *(const float4*)(W2c + (long)gm * 400 + gn0);          // W2[:, :200]
        } else if constexpr (MODE == 1) {
            if (gm < 400) *(float4*)(C + (long)gm * 1000 + gn0) = v;
            else          *(float4*)(C + (long)(gm - 400) * 1000 + 500 + gn0) = v;
        } else {
            float4 bb = *(const float4*)(bias + gn0);
            v.x += bb.x; v.y += bb.y; v.z += bb.z; v.w += bb.w;
            *(float4*)(C + (long)gm * 1400 + gn0) = v;
        }
    }
}

// ---------------------------------------------------------------------------
// Bias composition (1 block):
//   bbig[0:400]    = b2
//   bbig[400:900]  = (b2@Watt + batt) @ rel^T
//   bbig[900:1400] = b2[0:200] @ rel^T
// ---------------------------------------------------------------------------
__global__ __launch_bounds__(512) void k_bias(
    const float* __restrict__ b2, const float* __restrict__ Watt,
    const float* __restrict__ batt, const float* __restrict__ rel,
    float* __restrict__ bbig)
{
    __shared__ float b2s[400];
    __shared__ float b2att[200];
    int t = threadIdx.x;
    if (t < 400) { float v = b2[t]; b2s[t] = v; bbig[t] = v; }
    __syncthreads();
    if (t < 200) {
        float s = batt[t];
        for (int k = 0; k < 400; ++k) s += b2s[k] * Watt[k * 200 + t];
        b2att[t] = s;
    }
    __syncthreads();
    if (t < NRELS) {
        const float* rr = rel + (long)t * RDIM;
        float s1 = 0.f, s2 = 0.f;
        for (int n = 0; n < 200; ++n) {
            float rv = rr[n];
            s1 += b2att[n] * rv;
            s2 += b2s[n] * rv;
        }
        bbig[400 + t] = s1;
        bbig[900 + t] = s2;
    }
}

// ---------------------------------------------------------------------------
// K6: scores + masked softmax + entropy + rel softmax, all from Big row.
// Big[b] = [X2(400) | Srel_raw(500) | X2rel(500)].
// score[a] = ent_emb[e]·X2[200:400] + X2rel[r]   (1 VMEM load per action)
// ---------------------------------------------------------------------------
__global__ __launch_bounds__(512) void k_scores(
    const float* __restrict__ Big,
    const int* __restrict__ r_space, const int* __restrict__ e_space,
    const int* __restrict__ amask,
    const float* __restrict__ ent_emb,
    float* __restrict__ out_dist, float* __restrict__ out_ent,
    float* __restrict__ out_rel)
{
    int b = blockIdx.x, t = threadIdx.x;
    int wave = t >> 6, lane = t & 63;
    __shared__ __align__(16) float4 xt4[50];   // X2[200:400]
    __shared__ float xr[NRELS];                // X2rel row
    __shared__ float sc[ASZ];
    __shared__ int   smask[ASZ];
    __shared__ float red[8];

    const float* rowB = Big + (long)b * 1400;
    if (t < 50) xt4[t] = *(const float4*)(rowB + 200 + 4 * t);
    for (int i = t; i < NRELS; i += 512) xr[i] = rowB[900 + i];

    int abase = wave * 32;
    int r_idx = 0, e_idx = 0, mk = 0;
    if (lane < 32) {
        long base = (long)b * ASZ + abase + lane;
        r_idx = r_space[base];
        e_idx = e_space[base];
        mk    = amask[base];
        smask[abase + lane] = mk;
    }
    __syncthreads();

    float4 x = (lane < 50) ? xt4[lane] : make_float4(0.f, 0.f, 0.f, 0.f);

#pragma unroll
    for (int i = 0; i < 8; ++i) {
        float s[4] = {0.f, 0.f, 0.f, 0.f};
        int rj[4];
#pragma unroll
        for (int j = 0; j < 4; ++j) {
            int a = 4 * i + j;
            int m0 = __shfl(mk, a);
            rj[j]  = __shfl(r_idx, a);
            if (m0) {
                int e0 = __shfl(e_idx, a);
                if (lane < 50) {
                    float4 v = ((const float4*)(ent_emb + (long)e0 * EDIM))[lane];
                    s[j] = v.x * x.x + v.y * x.y + v.z * x.z + v.w * x.w;
                }
            }
        }
#pragma unroll
        for (int off = 32; off > 0; off >>= 1) {
            s[0] += __shfl_xor(s[0], off);
            s[1] += __shfl_xor(s[1], off);
            s[2] += __shfl_xor(s[2], off);
            s[3] += __shfl_xor(s[3], off);
        }
        if (lane == 0) {
            sc[abase + 4 * i + 0] = s[0] + xr[rj[0]];
            sc[abase + 4 * i + 1] = s[1] + xr[rj[1]];
            sc[abase + 4 * i + 2] = s[2] + xr[rj[2]];
            sc[abase + 4 * i + 3] = s[3] + xr[rj[3]];
        }
    }
    __syncthreads();

    // ---- masked softmax over 256 actions (threads 0..255) ----
    float v = -3.4e38f;
    float evv = 0.f;
    if (t < ASZ) v = smask[t] ? sc[t] : -1e31f;

    float m = v;
#pragma unroll
    for (int off = 32; off > 0; off >>= 1) m = fmaxf(m, __shfl_xor(m, off));
    if (t < ASZ && lane == 0) red[wave] = m;
    __syncthreads();
    float mm = fmaxf(fmaxf(red[0], red[1]), fmaxf(red[2], red[3]));
    __syncthreads();

    if (t < ASZ) evv = expf(v - mm);
    float ss = evv;
#pragma unroll
    for (int off = 32; off > 0; off >>= 1) ss += __shfl_xor(ss, off);
    if (t < ASZ && lane == 0) red[wave] = ss;
    __syncthreads();
    float tot = red[0] + red[1] + red[2] + red[3];
    __syncthreads();

    float term = 0.f;
    if (t < ASZ) {
        float p = evv / tot;
        out_dist[(long)b * ASZ + t] = p;
        term = p * logf(p + 1e-20f);
    }
#pragma unroll
    for (int off = 32; off > 0; off >>= 1) term += __shfl_xor(term, off);
    if (t < ASZ && lane == 0) red[wave] = term;
    __syncthreads();
    if (t == 0) out_ent[b] = -(red[0] + red[1] + red[2] + red[3]);
    __syncthreads();   // red[] reuse barrier (fixes latent race)

    // ---- relation-attention softmax from Big[b][400:900] ----
    float rv = (t < NRELS) ? rowB[400 + t] : -3.4e38f;

    float rm = rv;
#pragma unroll
    for (int off = 32; off > 0; off >>= 1) rm = fmaxf(rm, __shfl_xor(rm, off));
    if (lane == 0) red[wave] = rm;
    __syncthreads();
    rm = fmaxf(fmaxf(fmaxf(red[0], red[1]), fmaxf(red[2], red[3])),
               fmaxf(fmaxf(red[4], red[5]), fmaxf(red[6], red[7])));
    __syncthreads();

    float rev = (t < NRELS) ? expf(rv - rm) : 0.f;
    float rs = rev;
#pragma unroll
    for (int off = 32; off > 0; off >>= 1) rs += __shfl_xor(rs, off);
    if (lane == 0) red[wave] = rs;
    __syncthreads();
    rs = red[0] + red[1] + red[2] + red[3] + red[4] + red[5] + red[6] + red[7];
    if (t < NRELS) out_rel[(long)b * NRELS + t] = rev / rs;
}

// ---------------------------------------------------------------------------
extern "C" void kernel_launch(void* const* d_in, const int* in_sizes, int n_in,
                              void* d_out, int out_size, void* d_ws, size_t ws_size,
                              hipStream_t stream)
{
    const int*   e       = (const int*)  d_in[0];
    const int*   q       = (const int*)  d_in[1];
    const float* H       = (const float*)d_in[2];
    const int*   r_space = (const int*)  d_in[3];
    const int*   e_space = (const int*)  d_in[4];
    const int*   amask   = (const int*)  d_in[5];
    const float* ent     = (const float*)d_in[6];
    const float* rel     = (const float*)d_in[7];
    const float* W1      = (const float*)d_in[8];
    const float* b1      = (const float*)d_in[9];
    const float* W2      = (const float*)d_in[10];
    const float* b2      = (const float*)d_in[11];
    const float* Watt    = (const float*)d_in[12];
    const float* batt    = (const float*)d_in[13];

    float* out      = (float*)d_out;
    float* out_dist = out;                              // [1024,256]
    float* out_ent  = out + (long)BATCH * ASZ;          // [1024]
    float* out_rel  = out_ent + BATCH;                  // [1024,500]

    char* ws = (char*)d_ws;
    float* Xin    = (float*)(ws + 0);           // 3,276,800
    float* X1     = (float*)(ws + 3276800);     // 1,638,400
    float* Big    = (float*)(ws + 4915200);     // 5,734,400  [1024,1400]
    float* Astack = (float*)(ws + 10649600);    //   640,000  [800,200]
    float* Wcat   = (float*)(ws + 11289600);    // 1,600,000  [400,1000]
    float* bbig   = (float*)(ws + 12889600);    //     5,600
    float* Cp     = (float*)(ws + 12902400);    // 6,553,600  (G1 split-K)

    const bool sk = ws_size >= (size_t)19456000;
    const int ks1 = sk ? 4 : 1;

    // gather X_in
    k_gather_concat<<<BATCH, 256, 0, stream>>>(e, q, H, ent, rel, Xin);

    // weight composition prep
    k_gemm_s<0><<<dim3(4, 7), 256, 0, stream>>>(W2, Watt, nullptr, nullptr, Astack, W2);
    k_bias<<<1, 512, 0, stream>>>(b2, Watt, batt, rel, bbig);
    k_gemm_s<1><<<dim3(8, 13), 256, 0, stream>>>(Astack, rel, nullptr, nullptr, Wcat, nullptr);

    // X1 = relu(Xin @ W1 + b1)   [1024,400] K=800, split-K
    k_gemm<1,0><<<dim3(7, 16, ks1), 256, 0, stream>>>(Xin, W1, b1, X1, Cp,
                                                      BATCH, ACTDIM, INDIM, INDIM / ks1);
    if (sk) k_reduce<1,1><<<BATCH, 128, 0, stream>>>(Cp, b1, X1, BATCH, ACTDIM, ks1);

    // Big = X1 @ [W2 | Wrel | Wxrel] + bbig   [1024,1400] K=400
    k_gemm_s<2><<<dim3(22, 16), 256, 0, stream>>>(X1, W2, Wcat, bbig, Big, nullptr);

    // scores + softmaxes + entropy
    k_scores<<<BATCH, 512, 0, stream>>>(Big, r_space, e_space, amask, ent,
                                        out_dist, out_ent, out_rel);
}

// Round 7
// 102.897 us; speedup vs baseline: 1.9532x; 1.9532x over previous
//
#include <hip/hip_runtime.h>

#define BATCH   1024
#define ASZ     256
#define EDIM    200
#define RDIM    200
#define HDIM    400
#define ACTDIM  400   // E+R
#define INDIM   800   // E+H+R
#define NRELS   500

typedef __attribute__((ext_vector_type(8))) short short8v;   // 8 bf16 (4 VGPR)
typedef __attribute__((ext_vector_type(4))) float float4v;   // MFMA acc
typedef unsigned short u16;

__device__ __forceinline__ u16 f2bf(float f) {               // RNE fp32->bf16
    union { float f; unsigned u; } v; v.f = f;
    unsigned r = v.u + 0x7FFFu + ((v.u >> 16) & 1u);
    return (u16)(r >> 16);
}

// ---------------------------------------------------------------------------
// k_prep: (a) tile-transpose-convert W1[800,400]->W1t[400,800]bf16 and
// W2[400,400]->W2t[400,400]bf16; (b) BbigT rows 500..999 = [rel_bf | zeros];
// (c) brel = batt @ rel^T into bbig2[0:500], zeros bbig2[500:1000].
// All tasks independent (read only fp32 inputs).
// ---------------------------------------------------------------------------
__global__ __launch_bounds__(256) void k_prep(
    const float* __restrict__ W1, const float* __restrict__ W2,
    const float* __restrict__ batt, const float* __restrict__ rel,
    u16* __restrict__ W1t, u16* __restrict__ W2t,
    u16* __restrict__ BbigT, float* __restrict__ bbig2)
{
    int blk = blockIdx.x, t = threadIdx.x;
    __shared__ float tile[32][33];

    if (blk < 325) {                       // W1 transpose: 25 k-tiles x 13 n-tiles
        int tk = blk / 13, tn = blk % 13;
        int k0 = tk * 32, n0 = tn * 32;
        int i = t >> 3, j4 = (t & 7) * 4;
#pragma unroll
        for (int jj = 0; jj < 4; ++jj) {
            int n = n0 + j4 + jj;
            tile[i][j4 + jj] = (n < 400) ? W1[(long)(k0 + i) * 400 + n] : 0.f;
        }
        __syncthreads();
        int o = t >> 3;
        if (n0 + o < 400) {
            ushort4 u;
            u.x = f2bf(tile[j4 + 0][o]); u.y = f2bf(tile[j4 + 1][o]);
            u.z = f2bf(tile[j4 + 2][o]); u.w = f2bf(tile[j4 + 3][o]);
            *(ushort4*)(W1t + (long)(n0 + o) * 800 + k0 + j4) = u;
        }
    } else if (blk < 494) {                // W2 transpose: 13 x 13
        int idx = blk - 325;
        int tk = idx / 13, tn = idx % 13;
        int k0 = tk * 32, n0 = tn * 32;
        int i = t >> 3, j4 = (t & 7) * 4;
#pragma unroll
        for (int jj = 0; jj < 4; ++jj) {
            int n = n0 + j4 + jj;
            tile[i][j4 + jj] = (k0 + i < 400 && n < 400) ? W2[(long)(k0 + i) * 400 + n] : 0.f;
        }
        __syncthreads();
        int o = t >> 3;
        if (n0 + o < 400) {
#pragma unroll
            for (int jj = 0; jj < 4; ++jj) {
                int k = k0 + j4 + jj;
                if (k < 400) W2t[(long)(n0 + o) * 400 + k] = f2bf(tile[j4 + jj][o]);
            }
        }
    } else if (blk < 594) {                // BbigT rows 500..999
        int gid = (blk - 494) * 256 + t;
        for (int g = gid; g < 50000; g += 100 * 256) {
            int n = g / 100, kq = (g % 100) * 4;
            ushort4 u;
            u.x = (kq + 0 < 200) ? f2bf(rel[(long)n * 200 + kq + 0]) : (u16)0;
            u.y = (kq + 1 < 200) ? f2bf(rel[(long)n * 200 + kq + 1]) : (u16)0;
            u.z = (kq + 2 < 200) ? f2bf(rel[(long)n * 200 + kq + 2]) : (u16)0;
            u.w = (kq + 3 < 200) ? f2bf(rel[(long)n * 200 + kq + 3]) : (u16)0;
            *(ushort4*)(BbigT + (long)(500 + n) * 400 + kq) = u;
        }
    } else {                               // brel + zero pad
        __shared__ float bs[200];
        if (t < 200) bs[t] = batt[t];
        __syncthreads();
        for (int n = t; n < NRELS; n += 256) {
            const float* rr = rel + (long)n * RDIM;
            float s = 0.f;
            for (int k = 0; k < 200; ++k) s += bs[k] * rr[k];
            bbig2[n] = s;
        }
        for (int n = t; n < 500; n += 256) bbig2[500 + n] = 0.f;
    }
}

// ---------------------------------------------------------------------------
// k_gather: Xin_bf[b] = bf16([ent[e[b]] ; H[b] ; rel[q[b]]])
// ---------------------------------------------------------------------------
__global__ __launch_bounds__(256) void k_gather(
    const int* __restrict__ e, const int* __restrict__ q,
    const float* __restrict__ H,
    const float* __restrict__ ent_emb, const float* __restrict__ rel_emb,
    u16* __restrict__ Xin_bf)
{
    int b = blockIdx.x, t = threadIdx.x;
    if (t >= 200) return;
    const float4* E4 = (const float4*)(ent_emb + (long)e[b] * EDIM);  // 50
    const float4* Q4 = (const float4*)(rel_emb + (long)q[b] * RDIM);  // 50
    const float4* H4 = (const float4*)(H + (long)b * HDIM);           // 100
    float4 v = (t < 50) ? E4[t] : (t < 150) ? H4[t - 50] : Q4[t - 150];
    ushort4 u;
    u.x = f2bf(v.x); u.y = f2bf(v.y); u.z = f2bf(v.z); u.w = f2bf(v.w);
    *(ushort4*)(Xin_bf + (long)b * 800 + t * 4) = u;
}

// ---------------------------------------------------------------------------
// Staging: global (fp32 or bf16) row-major [R][K] -> LDS [64][40] bf16.
// 256 threads: row=t>>2 (64), kc=(t&3)*8. K is always a multiple of 8.
// ---------------------------------------------------------------------------
template<int SRCBF>
__device__ __forceinline__ void stage_tile(
    short* dst, const void* src, int ldk, int base, int R, int K, int k0, int t)
{
    const int row = t >> 2;
    const int kc  = (t & 3) * 8;
    const int gr  = base + row;
    const int gk  = k0 + kc;
    __attribute__((aligned(16))) u16 v[8];
    if (gr < R && gk + 8 <= K) {
        if (SRCBF) {
            const u16* p = (const u16*)src + (long)gr * ldk + gk;
            *(uint4*)v = *(const uint4*)p;
        } else {
            const float* p = (const float*)src + (long)gr * ldk + gk;
            float4 f0 = *(const float4*)p;
            float4 f1 = *(const float4*)(p + 4);
            v[0] = f2bf(f0.x); v[1] = f2bf(f0.y); v[2] = f2bf(f0.z); v[3] = f2bf(f0.w);
            v[4] = f2bf(f1.x); v[5] = f2bf(f1.y); v[6] = f2bf(f1.z); v[7] = f2bf(f1.w);
        }
    } else {
#pragma unroll
        for (int i = 0; i < 8; ++i) v[i] = 0;
    }
    *(uint4*)&dst[row * 40 + kc] = *(uint4*)v;
}

// ---------------------------------------------------------------------------
// bf16 MFMA GEMM: C = A[M,K] @ B^T (B stored [N][K]).
// 256 thr = 4 waves; 64x64 tile; wave -> 32x32 (2x2 16x16x32 frags).
// Verified layouts (learn_hip m89/m97): A lane: row=l&15, k=(l>>4)*8+j;
// B lane: col=l&15, k=(l>>4)*8+j (from [N][K] tile); D: col=l&15, row=(l>>4)*4+r.
// CT=1: fp32 partials to Cp slab z (split-K by K-steps).
// CT=2: bf16 transposed direct write CT2out[n*ldct + m] (weight prep).
// ---------------------------------------------------------------------------
template<int ABF, int BBF, int CT>
__global__ __launch_bounds__(256) void k_mgemm(
    const void* __restrict__ A, const void* __restrict__ B,
    float* __restrict__ Cp, u16* __restrict__ CT2out, int ldct,
    int M, int N, int K)
{
    __shared__ __align__(16) short As[64 * 40];
    __shared__ __align__(16) short Bs[64 * 40];

    const int t  = threadIdx.x;
    const int bn = blockIdx.x * 64, bm = blockIdx.y * 64;
    const int z  = blockIdx.z, nz = gridDim.z;
    const int tot = (K + 31) >> 5;
    const int s0 = (z * tot) / nz, s1 = ((z + 1) * tot) / nz;

    const int lane = t & 63, w = t >> 6;
    const int l15 = lane & 15, l4 = lane >> 4;
    const int wr = (w >> 1) * 32, wc = (w & 1) * 32;

    float4v acc00 = {0.f,0.f,0.f,0.f}, acc01 = {0.f,0.f,0.f,0.f};
    float4v acc10 = {0.f,0.f,0.f,0.f}, acc11 = {0.f,0.f,0.f,0.f};

    for (int s = s0; s < s1; ++s) {
        const int k0 = s << 5;
        stage_tile<ABF>(As, A, K, bm, M, K, k0, t);
        stage_tile<BBF>(Bs, B, K, bn, N, K, k0, t);
        __syncthreads();
        short8v a0 = *(short8v*)&As[(wr      + l15) * 40 + l4 * 8];
        short8v a1 = *(short8v*)&As[(wr + 16 + l15) * 40 + l4 * 8];
        short8v b0 = *(short8v*)&Bs[(wc      + l15) * 40 + l4 * 8];
        short8v b1 = *(short8v*)&Bs[(wc + 16 + l15) * 40 + l4 * 8];
        acc00 = __builtin_amdgcn_mfma_f32_16x16x32_bf16(a0, b0, acc00, 0, 0, 0);
        acc01 = __builtin_amdgcn_mfma_f32_16x16x32_bf16(a0, b1, acc01, 0, 0, 0);
        acc10 = __builtin_amdgcn_mfma_f32_16x16x32_bf16(a1, b0, acc10, 0, 0, 0);
        acc11 = __builtin_amdgcn_mfma_f32_16x16x32_bf16(a1, b1, acc11, 0, 0, 0);
        __syncthreads();
    }

    const int rm0 = bm + wr + l4 * 4;
    const int cn0 = bn + wc + l15;
    if (CT == 1) {
        float* dst = Cp + (long)z * M * N;
#pragma unroll
        for (int r = 0; r < 4; ++r) {
            int gm0 = rm0 + r, gm1 = rm0 + 16 + r;
            if (gm0 < M) {
                if (cn0 < N)      dst[(long)gm0 * N + cn0]      = acc00[r];
                if (cn0 + 16 < N) dst[(long)gm0 * N + cn0 + 16] = acc01[r];
            }
            if (gm1 < M) {
                if (cn0 < N)      dst[(long)gm1 * N + cn0]      = acc10[r];
                if (cn0 + 16 < N) dst[(long)gm1 * N + cn0 + 16] = acc11[r];
            }
        }
    } else {
#pragma unroll
        for (int r = 0; r < 4; ++r) {
            int gm0 = rm0 + r, gm1 = rm0 + 16 + r;
            if (gm0 < M) {
                if (cn0 < N)      CT2out[(long)cn0 * ldct + gm0]        = f2bf(acc00[r]);
                if (cn0 + 16 < N) CT2out[(long)(cn0 + 16) * ldct + gm0] = f2bf(acc01[r]);
            }
            if (gm1 < M) {
                if (cn0 < N)      CT2out[(long)cn0 * ldct + gm1]        = f2bf(acc10[r]);
                if (cn0 + 16 < N) CT2out[(long)(cn0 + 16) * ldct + gm1] = f2bf(acc11[r]);
            }
        }
    }
}

// ---------------------------------------------------------------------------
// Split-K reduce (+bias, relu). OUT: 0=fp32 only, 1=bf16 only, 2=both.
// Kernel-boundary coherence only (no fences — round-4 lesson).
// ---------------------------------------------------------------------------
template<int RELU, int OUT>
__global__ __launch_bounds__(128) void k_reduce2(
    const float* __restrict__ Cp, const float* __restrict__ bias,
    float* __restrict__ Cf, u16* __restrict__ Cb, int M, int N, int nks)
{
    int m = blockIdx.x;
    int nf4 = N >> 2;
    for (int f = threadIdx.x; f < nf4; f += 128) {
        long off = (long)m * N + f * 4;
        float4 s = *(const float4*)(Cp + off);
        for (int ks = 1; ks < nks; ++ks) {
            float4 v = *(const float4*)(Cp + (long)ks * M * N + off);
            s.x += v.x; s.y += v.y; s.z += v.z; s.w += v.w;
        }
        float4 bb = *(const float4*)(bias + f * 4);
        s.x += bb.x; s.y += bb.y; s.z += bb.z; s.w += bb.w;
        if (RELU) {
            s.x = fmaxf(s.x, 0.f); s.y = fmaxf(s.y, 0.f);
            s.z = fmaxf(s.z, 0.f); s.w = fmaxf(s.w, 0.f);
        }
        if (OUT != 1) *(float4*)(Cf + off) = s;
        if (OUT != 0) {
            ushort4 u;
            u.x = f2bf(s.x); u.y = f2bf(s.y); u.z = f2bf(s.z); u.w = f2bf(s.w);
            *(ushort4*)(Cb + off) = u;
        }
    }
}

// ---------------------------------------------------------------------------
// k_scores (round-6 verified): ent-gather dot + xr LDS lookup + masked
// softmax + entropy + rel softmax. Sources: X2 fp32, SX=[Srel_raw|X2rel].
// ---------------------------------------------------------------------------
__global__ __launch_bounds__(512) void k_scores(
    const float* __restrict__ X2, const float* __restrict__ SX,
    const int* __restrict__ r_space, const int* __restrict__ e_space,
    const int* __restrict__ amask,
    const float* __restrict__ ent_emb,
    float* __restrict__ out_dist, float* __restrict__ out_ent,
    float* __restrict__ out_rel)
{
    int b = blockIdx.x, t = threadIdx.x;
    int wave = t >> 6, lane = t & 63;
    __shared__ __align__(16) float4 xt4[50];   // X2[200:400]
    __shared__ float xr[NRELS];                // X2rel row
    __shared__ float sc[ASZ];
    __shared__ int   smask[ASZ];
    __shared__ float red[8];

    const float* rowX2 = X2 + (long)b * ACTDIM;
    const float* rowS  = SX + (long)b * 1000;
    if (t < 50) xt4[t] = *(const float4*)(rowX2 + 200 + 4 * t);
    for (int i = t; i < NRELS; i += 512) xr[i] = rowS[500 + i];

    int abase = wave * 32;
    int r_idx = 0, e_idx = 0, mk = 0;
    if (lane < 32) {
        long base = (long)b * ASZ + abase + lane;
        r_idx = r_space[base];
        e_idx = e_space[base];
        mk    = amask[base];
        smask[abase + lane] = mk;
    }
    __syncthreads();

    float4 x = (lane < 50) ? xt4[lane] : make_float4(0.f, 0.f, 0.f, 0.f);

#pragma unroll
    for (int i = 0; i < 8; ++i) {
        float s[4] = {0.f, 0.f, 0.f, 0.f};
        int rj[4];
#pragma unroll
        for (int j = 0; j < 4; ++j) {
            int a = 4 * i + j;
            int m0 = __shfl(mk, a);
            rj[j]  = __shfl(r_idx, a);
            if (m0) {
                int e0 = __shfl(e_idx, a);
                if (lane < 50) {
                    float4 v = ((const float4*)(ent_emb + (long)e0 * EDIM))[lane];
                    s[j] = v.x * x.x + v.y * x.y + v.z * x.z + v.w * x.w;
                }
            }
        }
#pragma unroll
        for (int off = 32; off > 0; off >>= 1) {
            s[0] += __shfl_xor(s[0], off);
            s[1] += __shfl_xor(s[1], off);
            s[2] += __shfl_xor(s[2], off);
            s[3] += __shfl_xor(s[3], off);
        }
        if (lane == 0) {
            sc[abase + 4 * i + 0] = s[0] + xr[rj[0]];
            sc[abase + 4 * i + 1] = s[1] + xr[rj[1]];
            sc[abase + 4 * i + 2] = s[2] + xr[rj[2]];
            sc[abase + 4 * i + 3] = s[3] + xr[rj[3]];
        }
    }
    __syncthreads();

    // ---- masked softmax over 256 actions ----
    float v = -3.4e38f;
    float evv = 0.f;
    if (t < ASZ) v = smask[t] ? sc[t] : -1e31f;

    float m = v;
#pragma unroll
    for (int off = 32; off > 0; off >>= 1) m = fmaxf(m, __shfl_xor(m, off));
    if (t < ASZ && lane == 0) red[wave] = m;
    __syncthreads();
    float mm = fmaxf(fmaxf(red[0], red[1]), fmaxf(red[2], red[3]));
    __syncthreads();

    if (t < ASZ) evv = expf(v - mm);
    float ss = evv;
#pragma unroll
    for (int off = 32; off > 0; off >>= 1) ss += __shfl_xor(ss, off);
    if (t < ASZ && lane == 0) red[wave] = ss;
    __syncthreads();
    float tot = red[0] + red[1] + red[2] + red[3];
    __syncthreads();

    float term = 0.f;
    if (t < ASZ) {
        float p = evv / tot;
        out_dist[(long)b * ASZ + t] = p;
        term = p * logf(p + 1e-20f);
    }
#pragma unroll
    for (int off = 32; off > 0; off >>= 1) term += __shfl_xor(term, off);
    if (t < ASZ && lane == 0) red[wave] = term;
    __syncthreads();
    if (t == 0) out_ent[b] = -(red[0] + red[1] + red[2] + red[3]);
    __syncthreads();   // red[] reuse barrier

    // ---- relation-attention softmax over SX[b][0:500] ----
    float rv = (t < NRELS) ? rowS[t] : -3.4e38f;

    float rm = rv;
#pragma unroll
    for (int off = 32; off > 0; off >>= 1) rm = fmaxf(rm, __shfl_xor(rm, off));
    if (lane == 0) red[wave] = rm;
    __syncthreads();
    rm = fmaxf(fmaxf(fmaxf(red[0], red[1]), fmaxf(red[2], red[3])),
               fmaxf(fmaxf(red[4], red[5]), fmaxf(red[6], red[7])));
    __syncthreads();

    float rev = (t < NRELS) ? expf(rv - rm) : 0.f;
    float rs = rev;
#pragma unroll
    for (int off = 32; off > 0; off >>= 1) rs += __shfl_xor(rs, off);
    if (lane == 0) red[wave] = rs;
    __syncthreads();
    rs = red[0] + red[1] + red[2] + red[3] + red[4] + red[5] + red[6] + red[7];
    if (t < NRELS) out_rel[(long)b * NRELS + t] = rev / rs;
}

// ---------------------------------------------------------------------------
extern "C" void kernel_launch(void* const* d_in, const int* in_sizes, int n_in,
                              void* d_out, int out_size, void* d_ws, size_t ws_size,
                              hipStream_t stream)
{
    const int*   e       = (const int*)  d_in[0];
    const int*   q       = (const int*)  d_in[1];
    const float* H       = (const float*)d_in[2];
    const int*   r_space = (const int*)  d_in[3];
    const int*   e_space = (const int*)  d_in[4];
    const int*   amask   = (const int*)  d_in[5];
    const float* ent     = (const float*)d_in[6];
    const float* rel     = (const float*)d_in[7];
    const float* W1      = (const float*)d_in[8];
    const float* b1      = (const float*)d_in[9];
    const float* W2      = (const float*)d_in[10];
    const float* b2      = (const float*)d_in[11];
    const float* Watt    = (const float*)d_in[12];
    const float* batt    = (const float*)d_in[13];

    float* out      = (float*)d_out;
    float* out_dist = out;                              // [1024,256]
    float* out_ent  = out + (long)BATCH * ASZ;          // [1024]
    float* out_rel  = out_ent + BATCH;                  // [1024,500]

    char* ws = (char*)d_ws;
    u16*   Xin_bf = (u16*)  (ws + 0);           // 1024x800x2  = 1,638,400
    u16*   X1_bf  = (u16*)  (ws + 1638400);     // 1024x400x2  =   819,200
    float* X2     = (float*)(ws + 2457600);     // 1024x400x4  = 1,638,400
    u16*   X2_bf  = (u16*)  (ws + 4096000);     // 1024x400x2  =   819,200
    u16*   W1t    = (u16*)  (ws + 4915200);     // 400x800x2   =   640,000
    u16*   W2t    = (u16*)  (ws + 5555200);     // 400x400x2   =   320,000
    u16*   BbigT  = (u16*)  (ws + 5875200);     // 1000x400x2  =   800,000
    float* bbig2  = (float*)(ws + 6675200);     // 1000x4      =     4,000
    float* SX     = (float*)(ws + 6679200);     // 1024x1000x4 = 4,096,000
    float* Cp     = (float*)(ws + 10775200);    // up to 8,192,000 (split-K)

    // 1) weight prep (transpose-convert + BbigT right half + brel)
    k_prep<<<595, 256, 0, stream>>>(W1, W2, batt, rel, W1t, W2t, BbigT, bbig2);

    // 2) BbigT[0:500][k] = (Watt @ rel^T)^T in bf16  (M=400,N=500,K=200)
    k_mgemm<0, 0, 2><<<dim3(8, 7, 1), 256, 0, stream>>>(
        Watt, rel, nullptr, BbigT, 400, 400, 500, 200);

    // 3) gather X_in (bf16)
    k_gather<<<BATCH, 256, 0, stream>>>(e, q, H, ent, rel, Xin_bf);

    // 4) X1 = relu(Xin @ W1 + b1)   [1024,400] K=800, split-K 4
    k_mgemm<1, 1, 1><<<dim3(7, 16, 4), 256, 0, stream>>>(
        Xin_bf, W1t, Cp, nullptr, 0, BATCH, ACTDIM, INDIM);
    k_reduce2<1, 1><<<BATCH, 128, 0, stream>>>(Cp, b1, nullptr, X1_bf, BATCH, ACTDIM, 4);

    // 5) X2 = X1 @ W2 + b2          [1024,400] K=400, split-K 4 (fp32 + bf16 out)
    k_mgemm<1, 1, 1><<<dim3(7, 16, 4), 256, 0, stream>>>(
        X1_bf, W2t, Cp, nullptr, 0, BATCH, ACTDIM, ACTDIM);
    k_reduce2<0, 2><<<BATCH, 128, 0, stream>>>(Cp, b2, X2, X2_bf, BATCH, ACTDIM, 4);

    // 6) SX = X2 @ BbigT^T + [brel|0]  [1024,1000] K=400, split-K 2
    //    cols 0..500 = Srel_raw, cols 500..1000 = X2rel
    k_mgemm<1, 1, 1><<<dim3(16, 16, 2), 256, 0, stream>>>(
        X2_bf, BbigT, Cp, nullptr, 0, BATCH, 1000, ACTDIM);
    k_reduce2<0, 0><<<BATCH, 128, 0, stream>>>(Cp, bbig2, SX, nullptr, BATCH, 1000, 2);

    // 7) scores + masked softmax + entropy + rel softmax
    k_scores<<<BATCH, 512, 0, stream>>>(X2, SX, r_space, e_space, amask, ent,
                                        out_dist, out_ent, out_rel);
}

// Round 8
// 89.548 us; speedup vs baseline: 2.2444x; 1.1491x over previous
//
#include <hip/hip_runtime.h>

#define BATCH   1024
#define ASZ     256
#define EDIM    200
#define RDIM    200
#define HDIM    400
#define ACTDIM  400   // E+R
#define INDIM   800   // E+H+R
#define NRELS   500

typedef __attribute__((ext_vector_type(8))) short short8v;   // 8 bf16 (4 VGPR)
typedef __attribute__((ext_vector_type(4))) float float4v;   // MFMA acc
typedef unsigned short u16;

__device__ __forceinline__ u16 f2bf(float f) {               // RNE fp32->bf16
    union { float f; unsigned u; } v; v.f = f;
    unsigned r = v.u + 0x7FFFu + ((v.u >> 16) & 1u);
    return (u16)(r >> 16);
}

// ---------------------------------------------------------------------------
// Shared MFMA GEMM body: C = A[M,K] @ B^T (B stored [N][K]).
// 256 thr = 4 waves; 64x64 tile; wave -> 32x32 (2x2 16x16x32 frags).
// Verified layouts (r7): A lane row=l&15,k=(l>>4)*8+j; B lane col=l&15 same k;
// D: col=l&15, row=(l>>4)*4+r.
// CT=1: fp32 partials to Cp slab z.  CT=2: bf16 transposed write.
// GAT=1: A is the virtual fp32 concat [ent[e]|H|rel[q]] (chunks never span
// boundaries: 200 and 600 are multiples of 8).
// ---------------------------------------------------------------------------
template<int ABF, int BBF, int CT, int GAT>
__device__ __forceinline__ void mgemm_body(
    const void* __restrict__ A, const void* __restrict__ B,
    float* __restrict__ Cp, u16* __restrict__ CTout, int ldct,
    int M, int N, int K, int bn, int bm, int z, int nz,
    const int* e_s, const int* q_s,
    const float* __restrict__ Hm, const float* __restrict__ ent,
    const float* __restrict__ rel,
    short* As, short* Bs, int t)
{
    const int tot = (K + 31) >> 5;
    const int s0 = (z * tot) / nz, s1 = ((z + 1) * tot) / nz;

    const int lane = t & 63, w = t >> 6;
    const int l15 = lane & 15, l4 = lane >> 4;
    const int wr = (w >> 1) * 32, wc = (w & 1) * 32;

    const int row = t >> 2;          // staging row 0..63
    const int kc  = (t & 3) * 8;     // staging k-chunk

    float4v acc00 = {0.f,0.f,0.f,0.f}, acc01 = {0.f,0.f,0.f,0.f};
    float4v acc10 = {0.f,0.f,0.f,0.f}, acc11 = {0.f,0.f,0.f,0.f};

    for (int s = s0; s < s1; ++s) {
        const int k0 = s << 5;
        // ---- stage A ----
        {
            const int gk = k0 + kc;
            __attribute__((aligned(16))) u16 v[8];
            if (GAT) {
                const float* p;
                if (gk < EDIM)            p = ent + (long)e_s[row] * EDIM + gk;
                else if (gk < EDIM+HDIM)  p = Hm  + (long)(bm + row) * HDIM + (gk - EDIM);
                else                      p = rel + (long)q_s[row] * RDIM + (gk - EDIM - HDIM);
                float4 f0 = *(const float4*)p;
                float4 f1 = *(const float4*)(p + 4);
                v[0]=f2bf(f0.x); v[1]=f2bf(f0.y); v[2]=f2bf(f0.z); v[3]=f2bf(f0.w);
                v[4]=f2bf(f1.x); v[5]=f2bf(f1.y); v[6]=f2bf(f1.z); v[7]=f2bf(f1.w);
            } else {
                const int gr = bm + row;
                if (gr < M && gk + 8 <= K) {
                    if (ABF) {
                        *(uint4*)v = *(const uint4*)((const u16*)A + (long)gr * K + gk);
                    } else {
                        const float* p = (const float*)A + (long)gr * K + gk;
                        float4 f0 = *(const float4*)p;
                        float4 f1 = *(const float4*)(p + 4);
                        v[0]=f2bf(f0.x); v[1]=f2bf(f0.y); v[2]=f2bf(f0.z); v[3]=f2bf(f0.w);
                        v[4]=f2bf(f1.x); v[5]=f2bf(f1.y); v[6]=f2bf(f1.z); v[7]=f2bf(f1.w);
                    }
                } else {
#pragma unroll
                    for (int i = 0; i < 8; ++i) v[i] = 0;
                }
            }
            *(uint4*)&As[row * 40 + kc] = *(uint4*)v;
        }
        // ---- stage B ----
        {
            const int gr = bn + row;
            const int gk = k0 + kc;
            __attribute__((aligned(16))) u16 v[8];
            if (gr < N && gk + 8 <= K) {
                if (BBF) {
                    *(uint4*)v = *(const uint4*)((const u16*)B + (long)gr * K + gk);
                } else {
                    const float* p = (const float*)B + (long)gr * K + gk;
                    float4 f0 = *(const float4*)p;
                    float4 f1 = *(const float4*)(p + 4);
                    v[0]=f2bf(f0.x); v[1]=f2bf(f0.y); v[2]=f2bf(f0.z); v[3]=f2bf(f0.w);
                    v[4]=f2bf(f1.x); v[5]=f2bf(f1.y); v[6]=f2bf(f1.z); v[7]=f2bf(f1.w);
                }
            } else {
#pragma unroll
                for (int i = 0; i < 8; ++i) v[i] = 0;
            }
            *(uint4*)&Bs[row * 40 + kc] = *(uint4*)v;
        }
        __syncthreads();
        short8v a0 = *(short8v*)&As[(wr      + l15) * 40 + l4 * 8];
        short8v a1 = *(short8v*)&As[(wr + 16 + l15) * 40 + l4 * 8];
        short8v b0 = *(short8v*)&Bs[(wc      + l15) * 40 + l4 * 8];
        short8v b1 = *(short8v*)&Bs[(wc + 16 + l15) * 40 + l4 * 8];
        acc00 = __builtin_amdgcn_mfma_f32_16x16x32_bf16(a0, b0, acc00, 0, 0, 0);
        acc01 = __builtin_amdgcn_mfma_f32_16x16x32_bf16(a0, b1, acc01, 0, 0, 0);
        acc10 = __builtin_amdgcn_mfma_f32_16x16x32_bf16(a1, b0, acc10, 0, 0, 0);
        acc11 = __builtin_amdgcn_mfma_f32_16x16x32_bf16(a1, b1, acc11, 0, 0, 0);
        __syncthreads();
    }

    const int rm0 = bm + wr + l4 * 4;
    const int cn0 = bn + wc + l15;
    if (CT == 1) {
        float* dst = Cp + (long)z * M * N;
#pragma unroll
        for (int r = 0; r < 4; ++r) {
            int gm0 = rm0 + r, gm1 = rm0 + 16 + r;
            if (gm0 < M) {
                if (cn0 < N)      dst[(long)gm0 * N + cn0]      = acc00[r];
                if (cn0 + 16 < N) dst[(long)gm0 * N + cn0 + 16] = acc01[r];
            }
            if (gm1 < M) {
                if (cn0 < N)      dst[(long)gm1 * N + cn0]      = acc10[r];
                if (cn0 + 16 < N) dst[(long)gm1 * N + cn0 + 16] = acc11[r];
            }
        }
    } else {
#pragma unroll
        for (int r = 0; r < 4; ++r) {
            int gm0 = rm0 + r, gm1 = rm0 + 16 + r;
            if (gm0 < M) {
                if (cn0 < N)      CTout[(long)cn0 * ldct + gm0]        = f2bf(acc00[r]);
                if (cn0 + 16 < N) CTout[(long)(cn0 + 16) * ldct + gm0] = f2bf(acc01[r]);
            }
            if (gm1 < M) {
                if (cn0 < N)      CTout[(long)cn0 * ldct + gm1]        = f2bf(acc10[r]);
                if (cn0 + 16 < N) CTout[(long)(cn0 + 16) * ldct + gm1] = f2bf(acc11[r]);
            }
        }
    }
}

// ---------------------------------------------------------------------------
// k_mgemm kernel wrapper (grid: bn, bm, z)
// ---------------------------------------------------------------------------
template<int ABF, int BBF, int CT, int GAT>
__global__ __launch_bounds__(256) void k_mgemm(
    const void* __restrict__ A, const void* __restrict__ B,
    float* __restrict__ Cp, u16* __restrict__ CTout, int ldct,
    int M, int N, int K,
    const int* __restrict__ eidx, const int* __restrict__ qidx,
    const float* __restrict__ Hm, const float* __restrict__ ent,
    const float* __restrict__ rel)
{
    __shared__ __align__(16) short As[64 * 40];
    __shared__ __align__(16) short Bs[64 * 40];
    __shared__ int e_s[64], q_s[64];
    const int t = threadIdx.x;
    const int bm = blockIdx.y * 64;
    if (GAT) {
        if (t < 64) {
            e_s[t] = eidx[bm + t];
            q_s[t] = qidx[bm + t];
        }
        __syncthreads();
    }
    mgemm_body<ABF, BBF, CT, GAT>(A, B, Cp, CTout, ldct, M, N, K,
                                  blockIdx.x * 64, bm, blockIdx.z, gridDim.z,
                                  e_s, q_s, Hm, ent, rel, As, Bs, t);
}

// ---------------------------------------------------------------------------
// k_prep_all: blocks 0..324  W1[800,400] -> W1t[400,800] bf16 (transpose)
//             blocks 325..493 W2[400,400] -> W2t[400,400] bf16 (transpose)
//             blocks 494..593 BbigT rows 500..999 = [rel_bf16 | zeros]
//             block  594      bbig2[0:500] = batt @ rel^T
//             blocks 595..650 BbigT rows 0..499 = (Watt @ rel^T)^T  (MFMA GEMM)
// ---------------------------------------------------------------------------
__global__ __launch_bounds__(256) void k_prep_all(
    const float* __restrict__ W1, const float* __restrict__ W2,
    const float* __restrict__ batt, const float* __restrict__ rel,
    const float* __restrict__ Watt,
    u16* __restrict__ W1t, u16* __restrict__ W2t,
    u16* __restrict__ BbigT, float* __restrict__ bbig2)
{
    __shared__ __align__(16) short As[64 * 40];
    __shared__ __align__(16) short Bs[64 * 40];
    __shared__ float tile[32][33];
    __shared__ float bs[200];

    int blk = blockIdx.x, t = threadIdx.x;

    if (blk < 325) {                       // W1 transpose: 25 k-tiles x 13 n-tiles
        int tk = blk / 13, tn = blk % 13;
        int k0 = tk * 32, n0 = tn * 32;
        int i = t >> 3, j4 = (t & 7) * 4;
#pragma unroll
        for (int jj = 0; jj < 4; ++jj) {
            int n = n0 + j4 + jj;
            tile[i][j4 + jj] = (n < 400) ? W1[(long)(k0 + i) * 400 + n] : 0.f;
        }
        __syncthreads();
        int o = t >> 3;
        if (n0 + o < 400) {
            ushort4 u;
            u.x = f2bf(tile[j4 + 0][o]); u.y = f2bf(tile[j4 + 1][o]);
            u.z = f2bf(tile[j4 + 2][o]); u.w = f2bf(tile[j4 + 3][o]);
            *(ushort4*)(W1t + (long)(n0 + o) * 800 + k0 + j4) = u;
        }
    } else if (blk < 494) {                // W2 transpose: 13 x 13
        int idx = blk - 325;
        int tk = idx / 13, tn = idx % 13;
        int k0 = tk * 32, n0 = tn * 32;
        int i = t >> 3, j4 = (t & 7) * 4;
#pragma unroll
        for (int jj = 0; jj < 4; ++jj) {
            int n = n0 + j4 + jj;
            tile[i][j4 + jj] = (k0 + i < 400 && n < 400) ? W2[(long)(k0 + i) * 400 + n] : 0.f;
        }
        __syncthreads();
        int o = t >> 3;
        if (n0 + o < 400) {
#pragma unroll
            for (int jj = 0; jj < 4; ++jj) {
                int k = k0 + j4 + jj;
                if (k < 400) W2t[(long)(n0 + o) * 400 + k] = f2bf(tile[j4 + jj][o]);
            }
        }
    } else if (blk < 594) {                // BbigT rows 500..999
        int gid = (blk - 494) * 256 + t;
        for (int g = gid; g < 50000; g += 100 * 256) {
            int n = g / 100, kq = (g % 100) * 4;
            ushort4 u;
            u.x = (kq + 0 < 200) ? f2bf(rel[(long)n * 200 + kq + 0]) : (u16)0;
            u.y = (kq + 1 < 200) ? f2bf(rel[(long)n * 200 + kq + 1]) : (u16)0;
            u.z = (kq + 2 < 200) ? f2bf(rel[(long)n * 200 + kq + 2]) : (u16)0;
            u.w = (kq + 3 < 200) ? f2bf(rel[(long)n * 200 + kq + 3]) : (u16)0;
            *(ushort4*)(BbigT + (long)(500 + n) * 400 + kq) = u;
        }
    } else if (blk == 594) {               // brel = batt @ rel^T
        if (t < 200) bs[t] = batt[t];
        __syncthreads();
        for (int n = t; n < NRELS; n += 256) {
            const float* rr = rel + (long)n * RDIM;
            float s = 0.f;
            for (int k = 0; k < 200; ++k) s += bs[k] * rr[k];
            bbig2[n] = s;
        }
    } else {                               // BbigT rows 0..499 (MFMA GEMM)
        int idx = blk - 595;               // 56 blocks: 8 bn x 7 bm
        int bn = (idx & 7) * 64, bm = (idx >> 3) * 64;
        mgemm_body<0, 0, 2, 0>(Watt, rel, nullptr, BbigT, 400,
                               400, 500, 200, bn, bm, 0, 1,
                               nullptr, nullptr, nullptr, nullptr, nullptr,
                               As, Bs, t);
    }
}

// ---------------------------------------------------------------------------
// Split-K reduce (+bias, relu). OUT: 0=fp32 only, 1=bf16 only, 2=both.
// ---------------------------------------------------------------------------
template<int RELU, int OUT>
__global__ __launch_bounds__(128) void k_reduce2(
    const float* __restrict__ Cp, const float* __restrict__ bias,
    float* __restrict__ Cf, u16* __restrict__ Cb, int M, int N, int nks)
{
    int m = blockIdx.x;
    int nf4 = N >> 2;
    for (int f = threadIdx.x; f < nf4; f += 128) {
        long off = (long)m * N + f * 4;
        float4 s = *(const float4*)(Cp + off);
        for (int ks = 1; ks < nks; ++ks) {
            float4 v = *(const float4*)(Cp + (long)ks * M * N + off);
            s.x += v.x; s.y += v.y; s.z += v.z; s.w += v.w;
        }
        float4 bb = *(const float4*)(bias + f * 4);
        s.x += bb.x; s.y += bb.y; s.z += bb.z; s.w += bb.w;
        if (RELU) {
            s.x = fmaxf(s.x, 0.f); s.y = fmaxf(s.y, 0.f);
            s.z = fmaxf(s.z, 0.f); s.w = fmaxf(s.w, 0.f);
        }
        if (OUT != 1) *(float4*)(Cf + off) = s;
        if (OUT != 0) {
            ushort4 u;
            u.x = f2bf(s.x); u.y = f2bf(s.y); u.z = f2bf(s.z); u.w = f2bf(s.w);
            *(ushort4*)(Cb + off) = u;
        }
    }
}

// ---------------------------------------------------------------------------
// k_scores: fused SX split-K reduce (2 slabs + brel bias) + ent-gather dot +
// masked softmax + entropy + rel softmax.
// ---------------------------------------------------------------------------
__global__ __launch_bounds__(512) void k_scores(
    const float* __restrict__ X2, const float* __restrict__ Cp,
    const float* __restrict__ brel,
    const int* __restrict__ r_space, const int* __restrict__ e_space,
    const int* __restrict__ amask,
    const float* __restrict__ ent_emb,
    float* __restrict__ out_dist, float* __restrict__ out_ent,
    float* __restrict__ out_rel)
{
    int b = blockIdx.x, t = threadIdx.x;
    int wave = t >> 6, lane = t & 63;
    __shared__ __align__(16) float4 xt4[50];   // X2[200:400]
    __shared__ float xr[NRELS];                // X2rel row
    __shared__ float sc[ASZ];
    __shared__ int   smask[ASZ];
    __shared__ float red[8];

    const float* rowX2 = X2 + (long)b * ACTDIM;
    const float* c0 = Cp + (long)b * 1000;
    const float* c1 = Cp + (long)BATCH * 1000 + (long)b * 1000;
    if (t < 50) xt4[t] = *(const float4*)(rowX2 + 200 + 4 * t);
    for (int i = t; i < NRELS; i += 512) xr[i] = c0[500 + i] + c1[500 + i];

    int abase = wave * 32;
    int r_idx = 0, e_idx = 0, mk = 0;
    if (lane < 32) {
        long base = (long)b * ASZ + abase + lane;
        r_idx = r_space[base];
        e_idx = e_space[base];
        mk    = amask[base];
        smask[abase + lane] = mk;
    }
    __syncthreads();

    float4 x = (lane < 50) ? xt4[lane] : make_float4(0.f, 0.f, 0.f, 0.f);

#pragma unroll
    for (int i = 0; i < 8; ++i) {
        float s[4] = {0.f, 0.f, 0.f, 0.f};
        int rj[4];
#pragma unroll
        for (int j = 0; j < 4; ++j) {
            int a = 4 * i + j;
            int m0 = __shfl(mk, a);
            rj[j]  = __shfl(r_idx, a);
            if (m0) {
                int e0 = __shfl(e_idx, a);
                if (lane < 50) {
                    float4 v = ((const float4*)(ent_emb + (long)e0 * EDIM))[lane];
                    s[j] = v.x * x.x + v.y * x.y + v.z * x.z + v.w * x.w;
                }
            }
        }
#pragma unroll
        for (int off = 32; off > 0; off >>= 1) {
            s[0] += __shfl_xor(s[0], off);
            s[1] += __shfl_xor(s[1], off);
            s[2] += __shfl_xor(s[2], off);
            s[3] += __shfl_xor(s[3], off);
        }
        if (lane == 0) {
            sc[abase + 4 * i + 0] = s[0] + xr[rj[0]];
            sc[abase + 4 * i + 1] = s[1] + xr[rj[1]];
            sc[abase + 4 * i + 2] = s[2] + xr[rj[2]];
            sc[abase + 4 * i + 3] = s[3] + xr[rj[3]];
        }
    }
    __syncthreads();

    // ---- masked softmax over 256 actions ----
    float v = -3.4e38f;
    float evv = 0.f;
    if (t < ASZ) v = smask[t] ? sc[t] : -1e31f;

    float m = v;
#pragma unroll
    for (int off = 32; off > 0; off >>= 1) m = fmaxf(m, __shfl_xor(m, off));
    if (t < ASZ && lane == 0) red[wave] = m;
    __syncthreads();
    float mm = fmaxf(fmaxf(red[0], red[1]), fmaxf(red[2], red[3]));
    __syncthreads();

    if (t < ASZ) evv = expf(v - mm);
    float ss = evv;
#pragma unroll
    for (int off = 32; off > 0; off >>= 1) ss += __shfl_xor(ss, off);
    if (t < ASZ && lane == 0) red[wave] = ss;
    __syncthreads();
    float tot = red[0] + red[1] + red[2] + red[3];
    __syncthreads();

    float term = 0.f;
    if (t < ASZ) {
        float p = evv / tot;
        out_dist[(long)b * ASZ + t] = p;
        term = p * logf(p + 1e-20f);
    }
#pragma unroll
    for (int off = 32; off > 0; off >>= 1) term += __shfl_xor(term, off);
    if (t < ASZ && lane == 0) red[wave] = term;
    __syncthreads();
    if (t == 0) out_ent[b] = -(red[0] + red[1] + red[2] + red[3]);
    __syncthreads();   // red[] reuse barrier

    // ---- relation-attention softmax: raw = c0+c1+brel ----
    float rv = (t < NRELS) ? (c0[t] + c1[t] + brel[t]) : -3.4e38f;

    float rm = rv;
#pragma unroll
    for (int off = 32; off > 0; off >>= 1) rm = fmaxf(rm, __shfl_xor(rm, off));
    if (lane == 0) red[wave] = rm;
    __syncthreads();
    rm = fmaxf(fmaxf(fmaxf(red[0], red[1]), fmaxf(red[2], red[3])),
               fmaxf(fmaxf(red[4], red[5]), fmaxf(red[6], red[7])));
    __syncthreads();

    float rev = (t < NRELS) ? expf(rv - rm) : 0.f;
    float rs = rev;
#pragma unroll
    for (int off = 32; off > 0; off >>= 1) rs += __shfl_xor(rs, off);
    if (lane == 0) red[wave] = rs;
    __syncthreads();
    rs = red[0] + red[1] + red[2] + red[3] + red[4] + red[5] + red[6] + red[7];
    if (t < NRELS) out_rel[(long)b * NRELS + t] = rev / rs;
}

// ---------------------------------------------------------------------------
extern "C" void kernel_launch(void* const* d_in, const int* in_sizes, int n_in,
                              void* d_out, int out_size, void* d_ws, size_t ws_size,
                              hipStream_t stream)
{
    const int*   e       = (const int*)  d_in[0];
    const int*   q       = (const int*)  d_in[1];
    const float* H       = (const float*)d_in[2];
    const int*   r_space = (const int*)  d_in[3];
    const int*   e_space = (const int*)  d_in[4];
    const int*   amask   = (const int*)  d_in[5];
    const float* ent     = (const float*)d_in[6];
    const float* rel     = (const float*)d_in[7];
    const float* W1      = (const float*)d_in[8];
    const float* b1      = (const float*)d_in[9];
    const float* W2      = (const float*)d_in[10];
    const float* b2      = (const float*)d_in[11];
    const float* Watt    = (const float*)d_in[12];
    const float* batt    = (const float*)d_in[13];

    float* out      = (float*)d_out;
    float* out_dist = out;                              // [1024,256]
    float* out_ent  = out + (long)BATCH * ASZ;          // [1024]
    float* out_rel  = out_ent + BATCH;                  // [1024,500]

    char* ws = (char*)d_ws;
    u16*   X1_bf  = (u16*)  (ws + 0);           // 1024x400x2  =   819,200
    float* X2     = (float*)(ws + 819200);      // 1024x400x4  = 1,638,400
    u16*   X2_bf  = (u16*)  (ws + 2457600);     // 1024x400x2  =   819,200
    u16*   W1t    = (u16*)  (ws + 3276800);     // 400x800x2   =   640,000
    u16*   W2t    = (u16*)  (ws + 3916800);     // 400x400x2   =   320,000
    u16*   BbigT  = (u16*)  (ws + 4236800);     // 1000x400x2  =   800,000
    float* bbig2  = (float*)(ws + 5036800);     // 500x4       =     2,000
    float* Cp     = (float*)(ws + 5242880);     // up to 8,192,000 (split-K)

    // 1) all weight prep: W1t, W2t, BbigT (both halves), brel
    k_prep_all<<<651, 256, 0, stream>>>(W1, W2, batt, rel, Watt,
                                        W1t, W2t, BbigT, bbig2);

    // 2) X1 = relu([ent|H|rel] @ W1 + b1)  [1024,400] K=800, split-K 4, gather fused
    k_mgemm<1, 1, 1, 1><<<dim3(7, 16, 4), 256, 0, stream>>>(
        nullptr, W1t, Cp, nullptr, 0, BATCH, ACTDIM, INDIM, e, q, H, ent, rel);
    k_reduce2<1, 1><<<BATCH, 128, 0, stream>>>(Cp, b1, nullptr, X1_bf, BATCH, ACTDIM, 4);

    // 3) X2 = X1 @ W2 + b2   [1024,400] K=400, split-K 4 (fp32 + bf16 out)
    k_mgemm<1, 1, 1, 0><<<dim3(7, 16, 4), 256, 0, stream>>>(
        X1_bf, W2t, Cp, nullptr, 0, BATCH, ACTDIM, ACTDIM,
        nullptr, nullptr, nullptr, nullptr, nullptr);
    k_reduce2<0, 2><<<BATCH, 128, 0, stream>>>(Cp, b2, X2, X2_bf, BATCH, ACTDIM, 4);

    // 4) SX partials = X2 @ BbigT^T  [1024,1000] K=400, split-K 2 (reduce fused in k_scores)
    k_mgemm<1, 1, 1, 0><<<dim3(16, 16, 2), 256, 0, stream>>>(
        X2_bf, BbigT, Cp, nullptr, 0, BATCH, 1000, ACTDIM,
        nullptr, nullptr, nullptr, nullptr, nullptr);

    // 5) scores + SX reduce + masked softmax + entropy + rel softmax
    k_scores<<<BATCH, 512, 0, stream>>>(X2, Cp, bbig2, r_space, e_space, amask,
                                        ent, out_dist, out_ent, out_rel);
}

// Round 9
// 80.477 us; speedup vs baseline: 2.4974x; 1.1127x over previous
//
#include <hip/hip_runtime.h>

#define BATCH   1024
#define ASZ     256
#define EDIM    200
#define RDIM    200
#define HDIM    400
#define ACTDIM  400   // E+R
#define INDIM   800   // E+H+R
#define NRELS   500

typedef __attribute__((ext_vector_type(8))) short short8v;   // 8 bf16 (4 VGPR)
typedef __attribute__((ext_vector_type(4))) float float4v;   // MFMA acc
typedef unsigned short u16;

__device__ __forceinline__ u16 f2bf(float f) {               // RNE fp32->bf16
    union { float f; unsigned u; } v; v.f = f;
    unsigned r = v.u + 0x7FFFu + ((v.u >> 16) & 1u);
    return (u16)(r >> 16);
}

// ---------------------------------------------------------------------------
// Shared MFMA GEMM body: C = A[M,K] @ B^T (B stored [N][K]).
// 256 thr = 4 waves; 64x64 tile; wave -> 32x32 (2x2 16x16x32 frags).
// Software-prefetched staging: step s+1's global loads issue right after the
// stage barrier, overlapping the MFMA block.
// CT=1: fp32 partials to Cp slab z.  CT=2: bf16 transposed write to CTout.
// CT=3: direct epilogue — bias (+relu) then fp32 Cf AND bf16 Cb.
// GAT=1: A is the virtual fp32 concat [ent[e]|H|rel[q]] (chunk-aligned).
// ---------------------------------------------------------------------------
template<int ABF, int BBF, int CT, int GAT, int RELU>
__device__ __forceinline__ void mgemm_body(
    const void* __restrict__ A, const void* __restrict__ B,
    float* __restrict__ Cp, u16* __restrict__ CTout, int ldct,
    const float* __restrict__ bias, float* __restrict__ Cf, u16* __restrict__ Cb,
    int M, int N, int K, int bn, int bm, int z, int nz,
    const int* e_s, const int* q_s,
    const float* __restrict__ Hm, const float* __restrict__ ent,
    const float* __restrict__ rel,
    short* As, short* Bs, int t)
{
    const int tot = (K + 31) >> 5;
    const int s0 = (z * tot) / nz, s1 = ((z + 1) * tot) / nz;

    const int lane = t & 63, w = t >> 6;
    const int l15 = lane & 15, l4 = lane >> 4;
    const int wr = (w >> 1) * 32, wc = (w & 1) * 32;

    const int row = t >> 2;          // staging row 0..63
    const int kc  = (t & 3) * 8;     // staging k-chunk

    auto loadA = [&](int s) -> uint4 {
        const int gk = (s << 5) + kc;
        __attribute__((aligned(16))) u16 v[8];
        if (GAT) {
            const float* p;
            if (gk < EDIM)              p = ent + (long)e_s[row] * EDIM + gk;
            else if (gk < EDIM + HDIM)  p = Hm  + (long)(bm + row) * HDIM + (gk - EDIM);
            else                        p = rel + (long)q_s[row] * RDIM + (gk - EDIM - HDIM);
            float4 f0 = *(const float4*)p;
            float4 f1 = *(const float4*)(p + 4);
            v[0]=f2bf(f0.x); v[1]=f2bf(f0.y); v[2]=f2bf(f0.z); v[3]=f2bf(f0.w);
            v[4]=f2bf(f1.x); v[5]=f2bf(f1.y); v[6]=f2bf(f1.z); v[7]=f2bf(f1.w);
            return *(uint4*)v;
        }
        const int gr = bm + row;
        if (gr < M && gk + 8 <= K) {
            if (ABF) return *(const uint4*)((const u16*)A + (long)gr * K + gk);
            const float* p = (const float*)A + (long)gr * K + gk;
            float4 f0 = *(const float4*)p;
            float4 f1 = *(const float4*)(p + 4);
            v[0]=f2bf(f0.x); v[1]=f2bf(f0.y); v[2]=f2bf(f0.z); v[3]=f2bf(f0.w);
            v[4]=f2bf(f1.x); v[5]=f2bf(f1.y); v[6]=f2bf(f1.z); v[7]=f2bf(f1.w);
            return *(uint4*)v;
        }
#pragma unroll
        for (int i = 0; i < 8; ++i) v[i] = 0;
        return *(uint4*)v;
    };
    auto loadB = [&](int s) -> uint4 {
        const int gk = (s << 5) + kc;
        const int gr = bn + row;
        __attribute__((aligned(16))) u16 v[8];
        if (gr < N && gk + 8 <= K) {
            if (BBF) return *(const uint4*)((const u16*)B + (long)gr * K + gk);
            const float* p = (const float*)B + (long)gr * K + gk;
            float4 f0 = *(const float4*)p;
            float4 f1 = *(const float4*)(p + 4);
            v[0]=f2bf(f0.x); v[1]=f2bf(f0.y); v[2]=f2bf(f0.z); v[3]=f2bf(f0.w);
            v[4]=f2bf(f1.x); v[5]=f2bf(f1.y); v[6]=f2bf(f1.z); v[7]=f2bf(f1.w);
            return *(uint4*)v;
        }
#pragma unroll
        for (int i = 0; i < 8; ++i) v[i] = 0;
        return *(uint4*)v;
    };

    float4v acc00 = {0.f,0.f,0.f,0.f}, acc01 = {0.f,0.f,0.f,0.f};
    float4v acc10 = {0.f,0.f,0.f,0.f}, acc11 = {0.f,0.f,0.f,0.f};

    uint4 ra = loadA(s0);
    uint4 rb = loadB(s0);

    for (int s = s0; s < s1; ++s) {
        *(uint4*)&As[row * 40 + kc] = ra;
        *(uint4*)&Bs[row * 40 + kc] = rb;
        __syncthreads();
        if (s + 1 < s1) {               // prefetch overlaps MFMA + barrier
            ra = loadA(s + 1);
            rb = loadB(s + 1);
        }
        short8v a0 = *(short8v*)&As[(wr      + l15) * 40 + l4 * 8];
        short8v a1 = *(short8v*)&As[(wr + 16 + l15) * 40 + l4 * 8];
        short8v b0 = *(short8v*)&Bs[(wc      + l15) * 40 + l4 * 8];
        short8v b1 = *(short8v*)&Bs[(wc + 16 + l15) * 40 + l4 * 8];
        acc00 = __builtin_amdgcn_mfma_f32_16x16x32_bf16(a0, b0, acc00, 0, 0, 0);
        acc01 = __builtin_amdgcn_mfma_f32_16x16x32_bf16(a0, b1, acc01, 0, 0, 0);
        acc10 = __builtin_amdgcn_mfma_f32_16x16x32_bf16(a1, b0, acc10, 0, 0, 0);
        acc11 = __builtin_amdgcn_mfma_f32_16x16x32_bf16(a1, b1, acc11, 0, 0, 0);
        __syncthreads();
    }

    const int rm0 = bm + wr + l4 * 4;
    const int cn0 = bn + wc + l15;
    if (CT == 1) {
        float* dst = Cp + (long)z * M * N;
#pragma unroll
        for (int r = 0; r < 4; ++r) {
            int gm0 = rm0 + r, gm1 = rm0 + 16 + r;
            if (gm0 < M) {
                if (cn0 < N)      dst[(long)gm0 * N + cn0]      = acc00[r];
                if (cn0 + 16 < N) dst[(long)gm0 * N + cn0 + 16] = acc01[r];
            }
            if (gm1 < M) {
                if (cn0 < N)      dst[(long)gm1 * N + cn0]      = acc10[r];
                if (cn0 + 16 < N) dst[(long)gm1 * N + cn0 + 16] = acc11[r];
            }
        }
    } else if (CT == 2) {
#pragma unroll
        for (int r = 0; r < 4; ++r) {
            int gm0 = rm0 + r, gm1 = rm0 + 16 + r;
            if (gm0 < M) {
                if (cn0 < N)      CTout[(long)cn0 * ldct + gm0]        = f2bf(acc00[r]);
                if (cn0 + 16 < N) CTout[(long)(cn0 + 16) * ldct + gm0] = f2bf(acc01[r]);
            }
            if (gm1 < M) {
                if (cn0 < N)      CTout[(long)cn0 * ldct + gm1]        = f2bf(acc10[r]);
                if (cn0 + 16 < N) CTout[(long)(cn0 + 16) * ldct + gm1] = f2bf(acc11[r]);
            }
        }
    } else {                            // CT==3: direct bias(+relu), dual output
        float bv0 = (cn0 < N)      ? bias[cn0]      : 0.f;
        float bv1 = (cn0 + 16 < N) ? bias[cn0 + 16] : 0.f;
#pragma unroll
        for (int r = 0; r < 4; ++r) {
            int gm0 = rm0 + r, gm1 = rm0 + 16 + r;
            if (gm0 < M) {
                if (cn0 < N) {
                    float v = acc00[r] + bv0;
                    if (RELU) v = fmaxf(v, 0.f);
                    Cf[(long)gm0 * N + cn0] = v;
                    Cb[(long)gm0 * N + cn0] = f2bf(v);
                }
                if (cn0 + 16 < N) {
                    float v = acc01[r] + bv1;
                    if (RELU) v = fmaxf(v, 0.f);
                    Cf[(long)gm0 * N + cn0 + 16] = v;
                    Cb[(long)gm0 * N + cn0 + 16] = f2bf(v);
                }
            }
            if (gm1 < M) {
                if (cn0 < N) {
                    float v = acc10[r] + bv0;
                    if (RELU) v = fmaxf(v, 0.f);
                    Cf[(long)gm1 * N + cn0] = v;
                    Cb[(long)gm1 * N + cn0] = f2bf(v);
                }
                if (cn0 + 16 < N) {
                    float v = acc11[r] + bv1;
                    if (RELU) v = fmaxf(v, 0.f);
                    Cf[(long)gm1 * N + cn0 + 16] = v;
                    Cb[(long)gm1 * N + cn0 + 16] = f2bf(v);
                }
            }
        }
    }
}

// ---------------------------------------------------------------------------
// k_mgemm kernel wrapper (grid: bn, bm, z)
// ---------------------------------------------------------------------------
template<int ABF, int BBF, int CT, int GAT, int RELU>
__global__ __launch_bounds__(256) void k_mgemm(
    const void* __restrict__ A, const void* __restrict__ B,
    float* __restrict__ Cp, u16* __restrict__ CTout, int ldct,
    const float* __restrict__ bias, float* __restrict__ Cf, u16* __restrict__ Cb,
    int M, int N, int K,
    const int* __restrict__ eidx, const int* __restrict__ qidx,
    const float* __restrict__ Hm, const float* __restrict__ ent,
    const float* __restrict__ rel)
{
    __shared__ __align__(16) short As[64 * 40];
    __shared__ __align__(16) short Bs[64 * 40];
    __shared__ int e_s[64], q_s[64];
    const int t = threadIdx.x;
    const int bm = blockIdx.y * 64;
    if (GAT) {
        if (t < 64) {
            e_s[t] = eidx[bm + t];
            q_s[t] = qidx[bm + t];
        }
        __syncthreads();
    }
    mgemm_body<ABF, BBF, CT, GAT, RELU>(A, B, Cp, CTout, ldct, bias, Cf, Cb,
                                        M, N, K, blockIdx.x * 64, bm,
                                        blockIdx.z, gridDim.z,
                                        e_s, q_s, Hm, ent, rel, As, Bs, t);
}

// ---------------------------------------------------------------------------
// k_prep_all: blocks 0..324  W1[800,400] -> W1t[400,800] bf16 (transpose)
//             blocks 325..493 W2[400,400] -> W2t[400,400] bf16 (transpose)
//             blocks 494..593 BbigT rows 500..999 = [rel_bf16 | zeros]
//             block  594      bbig2[0:500] = batt @ rel^T
//             blocks 595..650 BbigT rows 0..499 = (Watt @ rel^T)^T  (MFMA GEMM)
// ---------------------------------------------------------------------------
__global__ __launch_bounds__(256) void k_prep_all(
    const float* __restrict__ W1, const float* __restrict__ W2,
    const float* __restrict__ batt, const float* __restrict__ rel,
    const float* __restrict__ Watt,
    u16* __restrict__ W1t, u16* __restrict__ W2t,
    u16* __restrict__ BbigT, float* __restrict__ bbig2)
{
    __shared__ __align__(16) short As[64 * 40];
    __shared__ __align__(16) short Bs[64 * 40];
    __shared__ float tile[32][33];
    __shared__ float bs[200];

    int blk = blockIdx.x, t = threadIdx.x;

    if (blk < 325) {                       // W1 transpose: 25 k-tiles x 13 n-tiles
        int tk = blk / 13, tn = blk % 13;
        int k0 = tk * 32, n0 = tn * 32;
        int i = t >> 3, j4 = (t & 7) * 4;
#pragma unroll
        for (int jj = 0; jj < 4; ++jj) {
            int n = n0 + j4 + jj;
            tile[i][j4 + jj] = (n < 400) ? W1[(long)(k0 + i) * 400 + n] : 0.f;
        }
        __syncthreads();
        int o = t >> 3;
        if (n0 + o < 400) {
            ushort4 u;
            u.x = f2bf(tile[j4 + 0][o]); u.y = f2bf(tile[j4 + 1][o]);
            u.z = f2bf(tile[j4 + 2][o]); u.w = f2bf(tile[j4 + 3][o]);
            *(ushort4*)(W1t + (long)(n0 + o) * 800 + k0 + j4) = u;
        }
    } else if (blk < 494) {                // W2 transpose: 13 x 13
        int idx = blk - 325;
        int tk = idx / 13, tn = idx % 13;
        int k0 = tk * 32, n0 = tn * 32;
        int i = t >> 3, j4 = (t & 7) * 4;
#pragma unroll
        for (int jj = 0; jj < 4; ++jj) {
            int n = n0 + j4 + jj;
            tile[i][j4 + jj] = (k0 + i < 400 && n < 400) ? W2[(long)(k0 + i) * 400 + n] : 0.f;
        }
        __syncthreads();
        int o = t >> 3;
        if (n0 + o < 400) {
#pragma unroll
            for (int jj = 0; jj < 4; ++jj) {
                int k = k0 + j4 + jj;
                if (k < 400) W2t[(long)(n0 + o) * 400 + k] = f2bf(tile[j4 + jj][o]);
            }
        }
    } else if (blk < 594) {                // BbigT rows 500..999
        int gid = (blk - 494) * 256 + t;
        for (int g = gid; g < 50000; g += 100 * 256) {
            int n = g / 100, kq = (g % 100) * 4;
            ushort4 u;
            u.x = (kq + 0 < 200) ? f2bf(rel[(long)n * 200 + kq + 0]) : (u16)0;
            u.y = (kq + 1 < 200) ? f2bf(rel[(long)n * 200 + kq + 1]) : (u16)0;
            u.z = (kq + 2 < 200) ? f2bf(rel[(long)n * 200 + kq + 2]) : (u16)0;
            u.w = (kq + 3 < 200) ? f2bf(rel[(long)n * 200 + kq + 3]) : (u16)0;
            *(ushort4*)(BbigT + (long)(500 + n) * 400 + kq) = u;
        }
    } else if (blk == 594) {               // brel = batt @ rel^T
        if (t < 200) bs[t] = batt[t];
        __syncthreads();
        for (int n = t; n < NRELS; n += 256) {
            const float* rr = rel + (long)n * RDIM;
            float s = 0.f;
            for (int k = 0; k < 200; ++k) s += bs[k] * rr[k];
            bbig2[n] = s;
        }
    } else {                               // BbigT rows 0..499 (MFMA GEMM)
        int idx = blk - 595;               // 56 blocks: 8 bn x 7 bm
        int bn = (idx & 7) * 64, bm = (idx >> 3) * 64;
        mgemm_body<0, 0, 2, 0, 0>(Watt, rel, nullptr, BbigT, 400,
                                  nullptr, nullptr, nullptr,
                                  400, 500, 200, bn, bm, 0, 1,
                                  nullptr, nullptr, nullptr, nullptr, nullptr,
                                  As, Bs, t);
    }
}

// ---------------------------------------------------------------------------
// Split-K reduce (+bias, relu). OUT: 0=fp32 only, 1=bf16 only, 2=both.
// ---------------------------------------------------------------------------
template<int RELU, int OUT>
__global__ __launch_bounds__(128) void k_reduce2(
    const float* __restrict__ Cp, const float* __restrict__ bias,
    float* __restrict__ Cf, u16* __restrict__ Cb, int M, int N, int nks)
{
    int m = blockIdx.x;
    int nf4 = N >> 2;
    for (int f = threadIdx.x; f < nf4; f += 128) {
        long off = (long)m * N + f * 4;
        float4 s = *(const float4*)(Cp + off);
        for (int ks = 1; ks < nks; ++ks) {
            float4 v = *(const float4*)(Cp + (long)ks * M * N + off);
            s.x += v.x; s.y += v.y; s.z += v.z; s.w += v.w;
        }
        float4 bb = *(const float4*)(bias + f * 4);
        s.x += bb.x; s.y += bb.y; s.z += bb.z; s.w += bb.w;
        if (RELU) {
            s.x = fmaxf(s.x, 0.f); s.y = fmaxf(s.y, 0.f);
            s.z = fmaxf(s.z, 0.f); s.w = fmaxf(s.w, 0.f);
        }
        if (OUT != 1) *(float4*)(Cf + off) = s;
        if (OUT != 0) {
            ushort4 u;
            u.x = f2bf(s.x); u.y = f2bf(s.y); u.z = f2bf(s.z); u.w = f2bf(s.w);
            *(ushort4*)(Cb + off) = u;
        }
    }
}

// ---------------------------------------------------------------------------
// k_scores: fused SX split-K reduce + ent-gather dot (8 actions in flight,
// two-phase cross-lane reduction) + masked softmax + entropy + rel softmax.
// ---------------------------------------------------------------------------
__global__ __launch_bounds__(512) void k_scores(
    const float* __restrict__ X2, const float* __restrict__ Cp,
    const float* __restrict__ brel,
    const int* __restrict__ r_space, const int* __restrict__ e_space,
    const int* __restrict__ amask,
    const float* __restrict__ ent_emb,
    float* __restrict__ out_dist, float* __restrict__ out_ent,
    float* __restrict__ out_rel)
{
    int b = blockIdx.x, t = threadIdx.x;
    int wave = t >> 6, lane = t & 63;
    __shared__ __align__(16) float4 xt4[50];   // X2[200:400]
    __shared__ float xr[NRELS];                // X2rel row
    __shared__ float sc[ASZ];
    __shared__ int   smask[ASZ];
    __shared__ float red[8];

    const float* rowX2 = X2 + (long)b * ACTDIM;
    const float* c0 = Cp + (long)b * 1000;
    const float* c1 = Cp + (long)BATCH * 1000 + (long)b * 1000;
    if (t < 50) xt4[t] = *(const float4*)(rowX2 + 200 + 4 * t);
    for (int i = t; i < NRELS; i += 512) xr[i] = c0[500 + i] + c1[500 + i];

    int abase = wave * 32;
    int r_idx = 0, e_idx = 0, mk = 0;
    if (lane < 32) {
        long base = (long)b * ASZ + abase + lane;
        r_idx = r_space[base];
        e_idx = e_space[base];
        mk    = amask[base];
        smask[abase + lane] = mk;
    }
    __syncthreads();

    float4 x = (lane < 50) ? xt4[lane] : make_float4(0.f, 0.f, 0.f, 0.f);
    const int g = lane >> 4;

#pragma unroll
    for (int i = 0; i < 4; ++i) {              // 8 actions per iteration
        float s[8] = {0.f,0.f,0.f,0.f,0.f,0.f,0.f,0.f};
        int rj[8];
#pragma unroll
        for (int j = 0; j < 8; ++j) {
            int a = 8 * i + j;
            int m0 = __shfl(mk, a);
            rj[j]  = __shfl(r_idx, a);
            if (m0) {
                int e0 = __shfl(e_idx, a);
                if (lane < 50) {
                    float4 v = ((const float4*)(ent_emb + (long)e0 * EDIM))[lane];
                    s[j] = fmaf(v.x, x.x, fmaf(v.y, x.y, fmaf(v.z, x.z, v.w * x.w)));
                }
            }
        }
        // phase 1: reduce across the xor-16/32 lane groups (partials -> 16 lanes)
#pragma unroll
        for (int j = 0; j < 8; ++j) {
            s[j] += __shfl_xor(s[j], 32);
            s[j] += __shfl_xor(s[j], 16);
        }
        // phase 2: group g finishes action g (and 4+g)
        float v0 = (g == 0) ? s[0] : (g == 1) ? s[1] : (g == 2) ? s[2] : s[3];
        float v1 = (g == 0) ? s[4] : (g == 1) ? s[5] : (g == 2) ? s[6] : s[7];
#pragma unroll
        for (int off = 8; off > 0; off >>= 1) {
            v0 += __shfl_xor(v0, off);
            v1 += __shfl_xor(v1, off);
        }
        int r0sel = (g == 0) ? rj[0] : (g == 1) ? rj[1] : (g == 2) ? rj[2] : rj[3];
        int r1sel = (g == 0) ? rj[4] : (g == 1) ? rj[5] : (g == 2) ? rj[6] : rj[7];
        if ((lane & 15) == 0) {
            sc[abase + 8 * i + g]     = v0 + xr[r0sel];
            sc[abase + 8 * i + 4 + g] = v1 + xr[r1sel];
        }
    }
    __syncthreads();

    // ---- masked softmax over 256 actions ----
    float v = -3.4e38f;
    float evv = 0.f;
    if (t < ASZ) v = smask[t] ? sc[t] : -1e31f;

    float m = v;
#pragma unroll
    for (int off = 32; off > 0; off >>= 1) m = fmaxf(m, __shfl_xor(m, off));
    if (t < ASZ && lane == 0) red[wave] = m;
    __syncthreads();
    float mm = fmaxf(fmaxf(red[0], red[1]), fmaxf(red[2], red[3]));
    __syncthreads();

    if (t < ASZ) evv = expf(v - mm);
    float ss = evv;
#pragma unroll
    for (int off = 32; off > 0; off >>= 1) ss += __shfl_xor(ss, off);
    if (t < ASZ && lane == 0) red[wave] = ss;
    __syncthreads();
    float tot = red[0] + red[1] + red[2] + red[3];
    __syncthreads();

    float term = 0.f;
    if (t < ASZ) {
        float p = evv / tot;
        out_dist[(long)b * ASZ + t] = p;
        term = p * logf(p + 1e-20f);
    }
#pragma unroll
    for (int off = 32; off > 0; off >>= 1) term += __shfl_xor(term, off);
    if (t < ASZ && lane == 0) red[wave] = term;
    __syncthreads();
    if (t == 0) out_ent[b] = -(red[0] + red[1] + red[2] + red[3]);
    __syncthreads();   // red[] reuse barrier

    // ---- relation-attention softmax: raw = c0+c1+brel ----
    float rv = (t < NRELS) ? (c0[t] + c1[t] + brel[t]) : -3.4e38f;

    float rm = rv;
#pragma unroll
    for (int off = 32; off > 0; off >>= 1) rm = fmaxf(rm, __shfl_xor(rm, off));
    if (lane == 0) red[wave] = rm;
    __syncthreads();
    rm = fmaxf(fmaxf(fmaxf(red[0], red[1]), fmaxf(red[2], red[3])),
               fmaxf(fmaxf(red[4], red[5]), fmaxf(red[6], red[7])));
    __syncthreads();

    float rev = (t < NRELS) ? expf(rv - rm) : 0.f;
    float rs = rev;
#pragma unroll
    for (int off = 32; off > 0; off >>= 1) rs += __shfl_xor(rs, off);
    if (lane == 0) red[wave] = rs;
    __syncthreads();
    rs = red[0] + red[1] + red[2] + red[3] + red[4] + red[5] + red[6] + red[7];
    if (t < NRELS) out_rel[(long)b * NRELS + t] = rev / rs;
}

// ---------------------------------------------------------------------------
extern "C" void kernel_launch(void* const* d_in, const int* in_sizes, int n_in,
                              void* d_out, int out_size, void* d_ws, size_t ws_size,
                              hipStream_t stream)
{
    const int*   e       = (const int*)  d_in[0];
    const int*   q       = (const int*)  d_in[1];
    const float* H       = (const float*)d_in[2];
    const int*   r_space = (const int*)  d_in[3];
    const int*   e_space = (const int*)  d_in[4];
    const int*   amask   = (const int*)  d_in[5];
    const float* ent     = (const float*)d_in[6];
    const float* rel     = (const float*)d_in[7];
    const float* W1      = (const float*)d_in[8];
    const float* b1      = (const float*)d_in[9];
    const float* W2      = (const float*)d_in[10];
    const float* b2      = (const float*)d_in[11];
    const float* Watt    = (const float*)d_in[12];
    const float* batt    = (const float*)d_in[13];

    float* out      = (float*)d_out;
    float* out_dist = out;                              // [1024,256]
    float* out_ent  = out + (long)BATCH * ASZ;          // [1024]
    float* out_rel  = out_ent + BATCH;                  // [1024,500]

    char* ws = (char*)d_ws;
    u16*   X1_bf  = (u16*)  (ws + 0);           // 1024x400x2  =   819,200
    float* X2     = (float*)(ws + 819200);      // 1024x400x4  = 1,638,400
    u16*   X2_bf  = (u16*)  (ws + 2457600);     // 1024x400x2  =   819,200
    u16*   W1t    = (u16*)  (ws + 3276800);     // 400x800x2   =   640,000
    u16*   W2t    = (u16*)  (ws + 3916800);     // 400x400x2   =   320,000
    u16*   BbigT  = (u16*)  (ws + 4236800);     // 1000x400x2  =   800,000
    float* bbig2  = (float*)(ws + 5036800);     // 500x4       =     2,000
    float* Cp     = (float*)(ws + 5242880);     // up to 8,192,000 (split-K)

    // 1) all weight prep: W1t, W2t, BbigT (both halves), brel
    k_prep_all<<<651, 256, 0, stream>>>(W1, W2, batt, rel, Watt,
                                        W1t, W2t, BbigT, bbig2);

    // 2) X1 = relu([ent|H|rel] @ W1 + b1)  [1024,400] K=800, split-K 4, gather fused
    k_mgemm<1, 1, 1, 1, 0><<<dim3(7, 16, 4), 256, 0, stream>>>(
        nullptr, W1t, Cp, nullptr, 0, nullptr, nullptr, nullptr,
        BATCH, ACTDIM, INDIM, e, q, H, ent, rel);
    k_reduce2<1, 1><<<BATCH, 128, 0, stream>>>(Cp, b1, nullptr, X1_bf, BATCH, ACTDIM, 4);

    // 3) X2 = X1 @ W2 + b2  [1024,400] K=400, direct epilogue (fp32 + bf16)
    k_mgemm<1, 1, 3, 0, 0><<<dim3(7, 16, 1), 256, 0, stream>>>(
        X1_bf, W2t, nullptr, nullptr, 0, b2, X2, X2_bf,
        BATCH, ACTDIM, ACTDIM, nullptr, nullptr, nullptr, nullptr, nullptr);

    // 4) SX partials = X2 @ BbigT^T  [1024,1000] K=400, split-K 2 (reduce in k_scores)
    k_mgemm<1, 1, 1, 0, 0><<<dim3(16, 16, 2), 256, 0, stream>>>(
        X2_bf, BbigT, Cp, nullptr, 0, nullptr, nullptr, nullptr,
        BATCH, 1000, ACTDIM, nullptr, nullptr, nullptr, nullptr, nullptr);

    // 5) scores + SX reduce + masked softmax + entropy + rel softmax
    k_scores<<<BATCH, 512, 0, stream>>>(X2, Cp, bbig2, r_space, e_space, amask,
                                        ent, out_dist, out_ent, out_rel);
}